// Round 20
// baseline (1091.097 us; speedup 1.0000x reference)
//
#include <hip/hip_runtime.h>

#define Bdim 2
#define Tdim 2048
#define Cdim 2048
#define Hdim 32
#define Mdim (Bdim*Tdim)   // 4096

typedef unsigned short u16;
typedef short bf16x8 __attribute__((ext_vector_type(8)));
typedef float f32x2 __attribute__((ext_vector_type(2)));
typedef float f32x4 __attribute__((ext_vector_type(4)));

__device__ __forceinline__ u16 f2bf(float f) {
  unsigned u = __float_as_uint(f);
  u = (u + 0x7FFFu + ((u >> 16) & 1u)) >> 16;
  return (u16)u;
}
__device__ __forceinline__ float b2f(u16 h) {
  return __uint_as_float(((unsigned)h) << 16);
}
__device__ __forceinline__ float sigf(float x) { return 1.f / (1.f + expf(-x)); }

// async global->LDS, 16B per lane; LDS dest = wave-uniform base + lane*16
__device__ __forceinline__ void gld16(const u16* g, u16* l) {
  __builtin_amdgcn_global_load_lds(
      (const __attribute__((address_space(1))) unsigned int*)g,
      (__attribute__((address_space(3))) unsigned int*)l, 16, 0, 0);
}

// sum within each 16-lane DPP row via rotations: row_ror:8,4,2,1.
__device__ __forceinline__ float dpp_red16(float x) {
  int t = __builtin_amdgcn_mov_dpp(__float_as_int(x), 0x128, 0xF, 0xF, true);
  x += __int_as_float(t);
  t = __builtin_amdgcn_mov_dpp(__float_as_int(x), 0x124, 0xF, 0xF, true);
  x += __int_as_float(t);
  t = __builtin_amdgcn_mov_dpp(__float_as_int(x), 0x122, 0xF, 0xF, true);
  x += __int_as_float(t);
  t = __builtin_amdgcn_mov_dpp(__float_as_int(x), 0x121, 0xF, 0xF, true);
  x += __int_as_float(t);
  return x;
}

// full cross-half (lane^32) SUM. Preferred: permlane32_swap BUILTIN (compiler
// owns dataflow -> no register-aliasing hazard; res[0]+res[1] = lo+hi under
// either swap-direction convention). Fallback: proven __shfl_xor (ds_bpermute).
__device__ __forceinline__ float sum32(float x) {
#if __has_builtin(__builtin_amdgcn_permlane32_swap)
  typedef int int2v __attribute__((ext_vector_type(2)));
  int2v res = __builtin_amdgcn_permlane32_swap(__float_as_int(x), __float_as_int(x), false, false);
  return __int_as_float(res[0]) + __int_as_float(res[1]);
#else
  return x + __shfl_xor(x, 32);
#endif
}

// ---------------- diagnostic fill ----------------
__global__ __launch_bounds__(256) void fill_kernel(float* __restrict__ out, float v, int n) {
  int i = blockIdx.x * 256 + threadIdx.x;
  if (i < n) out[i] = v;
}

// ---------------- prep: token-shift mix; r/k/v/g as hi/lo split, w/a single ----------------
__global__ __launch_bounds__(256) void prep_kernel(
    const float* __restrict__ x, const float* __restrict__ shift,
    const float* __restrict__ mr, const float* __restrict__ mw,
    const float* __restrict__ mk, const float* __restrict__ mv,
    const float* __restrict__ ma, const float* __restrict__ mg,
    u16* __restrict__ xr_h, u16* __restrict__ xr_l,
    u16* __restrict__ xk_h, u16* __restrict__ xk_l,
    u16* __restrict__ xv_h, u16* __restrict__ xv_l,
    u16* __restrict__ xg_h, u16* __restrict__ xg_l,
    u16* __restrict__ xw, u16* __restrict__ xa)
{
  size_t idx = (size_t)blockIdx.x * 256 + threadIdx.x;  // < M*C
  int c = (int)(idx & (Cdim - 1));
  size_t row = idx >> 11;
  int t = (int)(row & (Tdim - 1));
  int b = (int)(row >> 11);
  float xc = x[idx];
  float xp = (t == 0) ? shift[(size_t)b * Cdim + c] : x[idx - Cdim];
  float xx = xp - xc;

  float vr = xc + xx * mr[c];
  u16 hr = f2bf(vr); xr_h[idx] = hr; xr_l[idx] = f2bf(vr - b2f(hr));
  float vk = xc + xx * mk[c];
  u16 hk = f2bf(vk); xk_h[idx] = hk; xk_l[idx] = f2bf(vk - b2f(hk));
  float vv = xc + xx * mv[c];
  u16 hv = f2bf(vv); xv_h[idx] = hv; xv_l[idx] = f2bf(vv - b2f(hv));
  float vg = xc + xx * mg[c];
  u16 hg = f2bf(vg); xg_h[idx] = hg; xg_l[idx] = f2bf(vg - b2f(hg));

  xw[idx] = f2bf(xc + xx * mw[c]);
  xa[idx] = f2bf(xc + xx * ma[c]);
}

// ---------------- weight packing ----------------
__global__ __launch_bounds__(256) void cast_split_kernel(
    const float* __restrict__ src, u16* __restrict__ hi, u16* __restrict__ lo)
{
  size_t i = (size_t)blockIdx.x * 256 + threadIdx.x;
  float v = src[i];
  u16 h = f2bf(v);
  hi[i] = h;
  lo[i] = f2bf(v - b2f(h));
}

// fused 3-weight split cast: Wr, Wk, Wv in one launch (partitioned by blockIdx).
__global__ __launch_bounds__(256) void cast3_kernel(
    const float* __restrict__ Wr, u16* __restrict__ rh, u16* __restrict__ rl,
    const float* __restrict__ Wk, u16* __restrict__ kh, u16* __restrict__ kl,
    const float* __restrict__ Wv, u16* __restrict__ vh, u16* __restrict__ vl)
{
  const size_t NB = (size_t)Cdim * Cdim / 256;   // blocks per weight
  size_t bid = blockIdx.x;
  const float* src; u16* hi; u16* lo;
  if (bid < NB)            { src = Wr; hi = rh; lo = rl; }
  else if (bid < 2 * NB)   { src = Wk; hi = kh; lo = kl; bid -= NB; }
  else                     { src = Wv; hi = vh; lo = vl; bid -= 2 * NB; }
  size_t i = bid * 256 + threadIdx.x;
  float v = src[i];
  u16 h = f2bf(v);
  hi[i] = h;
  lo[i] = f2bf(v - b2f(h));
}

// fused LoRA weight packs: 8 transposes in one launch, partitioned by blockIdx.
__global__ __launch_bounds__(256) void pack_all_kernel(
    const float* __restrict__ w1, const float* __restrict__ a1,
    const float* __restrict__ v1, const float* __restrict__ g1,
    const float* __restrict__ w2, const float* __restrict__ a2,
    const float* __restrict__ v2, const float* __restrict__ g2,
    u16* __restrict__ w1t, u16* __restrict__ a1t, u16* __restrict__ v1t,
    u16* __restrict__ g1t_h, u16* __restrict__ g1t_l,
    u16* __restrict__ w2t, u16* __restrict__ a2t, u16* __restrict__ v2t,
    u16* __restrict__ g2t_h, u16* __restrict__ g2t_l)
{
  int bid = blockIdx.x;
  const float* src; u16* dh; u16* dl = nullptr;
  int K, Nsrc; size_t idx0;
  if (bid < 1024)      { src = w1; dh = w1t;   K = 2048; Nsrc = 64;   idx0 = (size_t)bid * 256; }
  else if (bid < 2048) { src = a1; dh = a1t;   K = 2048; Nsrc = 64;   idx0 = (size_t)(bid - 1024) * 256; }
  else if (bid < 3072) { src = v1; dh = v1t;   K = 2048; Nsrc = 32;   idx0 = (size_t)(bid - 2048) * 256; }
  else if (bid < 4096) { src = g1; dh = g1t_h; dl = g1t_l; K = 2048; Nsrc = 128; idx0 = (size_t)(bid - 3072) * 256; }
  else if (bid < 4608) { src = w2; dh = w2t;   K = 64;   Nsrc = 2048; idx0 = (size_t)(bid - 4096) * 256; }
  else if (bid < 5120) { src = a2; dh = a2t;   K = 64;   Nsrc = 2048; idx0 = (size_t)(bid - 4608) * 256; }
  else if (bid < 5376) { src = v2; dh = v2t;   K = 32;   Nsrc = 2048; idx0 = (size_t)(bid - 5120) * 256; }
  else                 { src = g2; dh = g2t_h; dl = g2t_l; K = 128;  Nsrc = 2048; idx0 = (size_t)(bid - 5376) * 256; }
  size_t idx = idx0 + threadIdx.x;
  int n = (int)(idx / K);
  int kk = (int)(idx - (size_t)n * K);
  float v = (n < Nsrc) ? src[(size_t)kk * Nsrc + n] : 0.f;
  u16 h = f2bf(v);
  dh[idx] = h;
  if (dl) dl[idx] = f2bf(v - b2f(h));
}

// LDS bank swizzle (both-sides, rule 21): content[row][slot] = global[row][slot^(row&3)]
// staging source slot: (tid&3)^((tid>>2)&3); fragment read col: fk ^ ((fr&3)<<3).

// ================= plain bf16 GEMM, 128x128 tile, BK=32, 2-phase double-buffered =================
// EP: 1 tanh->bf16 | 2 none/tanh(act)->bf16 | 3 ew=bf16(0.6065*sig(bias[n]+x))
//     4 a=f32 sig(bias[n]+x)     | 5 vmix: f32 out = aux1 + (aux2-aux1)*sig(bias[n]+x)
template <int EP>
__device__ __forceinline__ void gemm_plain_body(
    const u16* __restrict__ A, const u16* __restrict__ B, void* __restrict__ Cv,
    const float* __restrict__ bias, const float* __restrict__ aux1,
    const float* __restrict__ aux2, int K, int Nact, int ldC, int act)
{
  __shared__ u16 As[2][128][32];
  __shared__ u16 Bs[2][128][32];
  int tid = threadIdx.x;
  int lane = tid & 63, wave = tid >> 6;
  int wm = wave >> 1, wn = wave & 1;
  int bm = blockIdx.x * 128, bn = blockIdx.y * 128;
  f32x4 zero = {0.f, 0.f, 0.f, 0.f};
  f32x4 acc[4][4];
#pragma unroll
  for (int i = 0; i < 4; i++)
#pragma unroll
    for (int j = 0; j < 4; j++) acc[i][j] = zero;
  int srow = tid >> 2;
  int sslot = tid & 3;
  int scol = (sslot ^ (srow & 3)) << 3;     // swizzled source col (u16)
  int dcol = sslot << 3;                    // linear LDS dest col
  const u16* gA  = A + (size_t)(bm + srow) * K + scol;
  const u16* gA2 = A + (size_t)(bm + 64 + srow) * K + scol;
  const u16* gB  = B + (size_t)(bn + srow) * K + scol;
  const u16* gB2 = B + (size_t)(bn + 64 + srow) * K + scol;
  int fr = lane & 15;
  int fk = ((lane >> 4) << 3) ^ ((fr & 3) << 3);   // swizzled fragment col

#define STAGEP(buf, kk) { \
  gld16(gA + (kk), &As[buf][srow][dcol]); \
  gld16(gA2 + (kk), &As[buf][64 + srow][dcol]); \
  gld16(gB + (kk), &Bs[buf][srow][dcol]); \
  gld16(gB2 + (kk), &Bs[buf][64 + srow][dcol]); }

  STAGEP(0, 0)
  __syncthreads();
  int cur = 0;
  for (int k0 = 0; k0 < K; k0 += 32) {
    if (k0 + 32 < K) STAGEP(cur ^ 1, k0 + 32)
    bf16x8 af[4], bfv[4];
#pragma unroll
    for (int i = 0; i < 4; i++) af[i] = *(const bf16x8*)&As[cur][wm * 64 + i * 16 + fr][fk];
#pragma unroll
    for (int j = 0; j < 4; j++) bfv[j] = *(const bf16x8*)&Bs[cur][wn * 64 + j * 16 + fr][fk];
#pragma unroll
    for (int i = 0; i < 4; i++)
#pragma unroll
      for (int j = 0; j < 4; j++)
        acc[i][j] = __builtin_amdgcn_mfma_f32_16x16x32_bf16(af[i], bfv[j], acc[i][j], 0, 0, 0);
    __syncthreads();   // drains vmcnt (stage) + lgkmcnt; next tile ready
    cur ^= 1;
  }
#undef STAGEP
  int rb = (lane >> 4) << 2;   // C/D: col=lane&15, row=(lane>>4)*4+reg [m89/m91]
  int cc = lane & 15;
#pragma unroll
  for (int i = 0; i < 4; i++) {
    int mm = bm + wm * 64 + i * 16 + rb;
#pragma unroll
    for (int j = 0; j < 4; j++) {
      int nn = bn + wn * 64 + j * 16 + cc;
      if (nn < Nact) {
#pragma unroll
        for (int r = 0; r < 4; r++) {
          float val = acc[i][j][r];
          size_t oidx = (size_t)(mm + r) * ldC + nn;
          if (EP == 1) ((u16*)Cv)[oidx] = f2bf(tanhf(val));
          else if (EP == 2) {
            if (act == 1) val = tanhf(val);
            ((u16*)Cv)[oidx] = f2bf(val);
          }
          else if (EP == 3) ((u16*)Cv)[oidx] = f2bf(0.60653065971f * sigf(bias[nn] + val));
          else if (EP == 4) ((float*)Cv)[oidx] = sigf(bias[nn] + val);
          else if (EP == 5) {
            float vraw = aux1[oidx], vf = aux2[oidx];
            ((float*)Cv)[oidx] = vraw + (vf - vraw) * sigf(bias[nn] + val);
          }
        }
      }
    }
  }
}

// fused LoRA-1 plain (z: 0=w tanh, 1=a, 2=v), K=2048
__global__ __launch_bounds__(256) void lora1_kernel(
    const u16* A0, const u16* A1, const u16* A2,
    const u16* B0, const u16* B1, const u16* B2,
    u16* C0, u16* C1, u16* C2, int N0, int N1, int N2)
{
  int z = blockIdx.z;
  const u16* A = (z == 0) ? A0 : (z == 1) ? A1 : A2;
  const u16* B = (z == 0) ? B0 : (z == 1) ? B1 : B2;
  u16* C      = (z == 0) ? C0 : (z == 1) ? C1 : C2;
  int Nact    = (z == 0) ? N0 : (z == 1) ? N1 : N2;
  int act     = (z == 0) ? 1 : 0;
  gemm_plain_body<2>(A, B, C, nullptr, nullptr, nullptr, 2048, Nact, Nact, act);
}

// fused LoRA-2 (z: 0=ew EP3 K=64, 1=a EP4 K=64, 2=vmix EP5 K=32)
__global__ __launch_bounds__(256) void lora2_kernel(
    const u16* Aw, const u16* Aa, const u16* Av,
    const u16* Bw, const u16* Ba, const u16* Bv,
    u16* Cw, float* Ca, float* Cv,
    const float* w0, const float* a0, const float* v0,
    const float* vfirst)
{
  int z = blockIdx.z;
  if (z == 0)
    gemm_plain_body<3>(Aw, Bw, Cw, w0, nullptr, nullptr, 64, Cdim, Cdim, 0);
  else if (z == 1)
    gemm_plain_body<4>(Aa, Ba, Ca, a0, nullptr, nullptr, 64, Cdim, Cdim, 0);
  else
    gemm_plain_body<5>(Av, Bv, Cv, v0, Cv, vfirst, 32, Cdim, Cdim, 0);
}

// ================= split-bf16 GEMM (~f32): D = Ah*Bh + Ah*Bl + Al*Bh =================
// 2-phase double-buffered (64KB LDS, 2 blocks/CU). EP: 0 f32 | 1 sigmoid -> hi/lo pair
template <int EP>
__global__ __launch_bounds__(256) void gemm_split(
    const u16* __restrict__ Ah, const u16* __restrict__ Al,
    const u16* __restrict__ Bh, const u16* __restrict__ Bl,
    void* __restrict__ C1, u16* __restrict__ C2, int K, int Nact, int ldC)
{
  __shared__ u16 Ash[2][128][32];
  __shared__ u16 Asl[2][128][32];
  __shared__ u16 Bsh[2][128][32];
  __shared__ u16 Bsl[2][128][32];
  int tid = threadIdx.x;
  int lane = tid & 63, wave = tid >> 6;
  int wm = wave >> 1, wn = wave & 1;
  int bm = blockIdx.x * 128, bn = blockIdx.y * 128;
  f32x4 zero = {0.f, 0.f, 0.f, 0.f};
  f32x4 acc[4][4];
#pragma unroll
  for (int i = 0; i < 4; i++)
#pragma unroll
    for (int j = 0; j < 4; j++) acc[i][j] = zero;
  int srow = tid >> 2;
  int sslot = tid & 3;
  int scol = (sslot ^ (srow & 3)) << 3;
  int dcol = sslot << 3;
  size_t ga  = (size_t)(bm + srow) * K + scol;
  size_t ga2 = (size_t)(bm + 64 + srow) * K + scol;
  size_t gb  = (size_t)(bn + srow) * K + scol;
  size_t gb2 = (size_t)(bn + 64 + srow) * K + scol;
  int fr = lane & 15;
  int fk = ((lane >> 4) << 3) ^ ((fr & 3) << 3);

#define STAGES(buf, kk) { \
  gld16(Ah + ga + (kk), &Ash[buf][srow][dcol]); \
  gld16(Ah + ga2 + (kk), &Ash[buf][64 + srow][dcol]); \
  gld16(Al + ga + (kk), &Asl[buf][srow][dcol]); \
  gld16(Al + ga2 + (kk), &Asl[buf][64 + srow][dcol]); \
  gld16(Bh + gb + (kk), &Bsh[buf][srow][dcol]); \
  gld16(Bh + gb2 + (kk), &Bsh[buf][64 + srow][dcol]); \
  gld16(Bl + gb + (kk), &Bsl[buf][srow][dcol]); \
  gld16(Bl + gb2 + (kk), &Bsl[buf][64 + srow][dcol]); }

  STAGES(0, 0)
  __syncthreads();
  int cur = 0;
  for (int k0 = 0; k0 < K; k0 += 32) {
    if (k0 + 32 < K) STAGES(cur ^ 1, k0 + 32)
    bf16x8 fah[4], fal[4], fbh[4], fbl[4];
#pragma unroll
    for (int i = 0; i < 4; i++) {
      fah[i] = *(const bf16x8*)&Ash[cur][wm * 64 + i * 16 + fr][fk];
      fal[i] = *(const bf16x8*)&Asl[cur][wm * 64 + i * 16 + fr][fk];
    }
#pragma unroll
    for (int j = 0; j < 4; j++) {
      fbh[j] = *(const bf16x8*)&Bsh[cur][wn * 64 + j * 16 + fr][fk];
      fbl[j] = *(const bf16x8*)&Bsl[cur][wn * 64 + j * 16 + fr][fk];
    }
#pragma unroll
    for (int i = 0; i < 4; i++)
#pragma unroll
      for (int j = 0; j < 4; j++) {
        acc[i][j] = __builtin_amdgcn_mfma_f32_16x16x32_bf16(fah[i], fbh[j], acc[i][j], 0, 0, 0);
        acc[i][j] = __builtin_amdgcn_mfma_f32_16x16x32_bf16(fah[i], fbl[j], acc[i][j], 0, 0, 0);
        acc[i][j] = __builtin_amdgcn_mfma_f32_16x16x32_bf16(fal[i], fbh[j], acc[i][j], 0, 0, 0);
      }
    __syncthreads();
    cur ^= 1;
  }
#undef STAGES
  int rb = (lane >> 4) << 2;
  int cc = lane & 15;
#pragma unroll
  for (int i = 0; i < 4; i++) {
    int mm = bm + wm * 64 + i * 16 + rb;
#pragma unroll
    for (int j = 0; j < 4; j++) {
      int nn = bn + wn * 64 + j * 16 + cc;
      if (nn < Nact) {
#pragma unroll
        for (int r = 0; r < 4; r++) {
          float val = acc[i][j][r];
          size_t oidx = (size_t)(mm + r) * ldC + nn;
          if (EP == 0) ((float*)C1)[oidx] = val;
          else {
            float s = sigf(val);
            u16 h = f2bf(s);
            ((u16*)C1)[oidx] = h;
            C2[oidx] = f2bf(s - b2f(h));
          }
        }
      }
    }
  }
}

// ---------------- post: kk-norm + ain/bin + k-scale (one wave per (m,h)) ----------------
__global__ __launch_bounds__(256) void post_kernel(
    float* __restrict__ k, const float* __restrict__ a,
    const float* __restrict__ k_k, const float* __restrict__ k_a,
    float* __restrict__ ain, float* __restrict__ bin)
{
  int gid = blockIdx.x * 4 + (threadIdx.x >> 6);
  int lane = threadIdx.x & 63;
  int m = gid >> 5, h = gid & 31;
  int c = h * 64 + lane;
  size_t idx = (size_t)m * Cdim + c;

  float kr = k[idx];
  float av = a[idx];

  float kkv = kr * k_k[c];
  float ss = kkv * kkv;
#pragma unroll
  for (int off = 32; off; off >>= 1) ss += __shfl_xor(ss, off);
  float kkn = kkv / fmaxf(sqrtf(ss), 1e-12f);

  ain[idx] = -kkn;
  bin[idx] = kkn * av;
  k[idx] = kr * (1.f + (av - 1.f) * k_a[c]);
}

// ---------------- scan v15: LDS-shared 8-wave blocks + builtin permlane reduce ----------------
// grid = 256 blocks (bh = blk&63 -> 4 blocks/bh), 512 threads (8 waves, 2/SIMD).
// Per-wave layout: jci on lane bits {0,1,2,3,5}, lr on bit 4; i = q4*16+wv*2+lr.
// LDS per slot (45056B): AK[32][32] f32x4 @0; BR @16384; V @32768; E @40960.
// Cross-lane: dpp_red16 (bits 0-3) + sum32 (bit 5; builtin permlane or shfl fallback).
#define SG 32
__global__ __launch_bounds__(512) void scan_kernel(
    const float* __restrict__ r, const u16* __restrict__ ew,
    const float* __restrict__ k, const float* __restrict__ v,
    const float* __restrict__ ain, const float* __restrict__ bin,
    const float* __restrict__ S0, float* __restrict__ o)
{
  int bh = blockIdx.x & 63;
  int q4 = blockIdx.x >> 6;       // 0..3
  int tid = threadIdx.x;
  int wv = tid >> 6;              // 0..7
  int lane = tid & 63;
  int jci = (lane & 15) | ((lane >> 1) & 16);  // j-chunk 0..31
  int lr = (lane >> 4) & 1;                    // row bit
  int i = q4 * 16 + wv * 2 + lr;  // channel row 0..63
  int cb = (bh & 31) * 64;        // channel base
  size_t mbase = (size_t)(bh >> 5) * Tdim;   // row base in [M][C]

  float s0, s1;
  {
    const float* sp = S0 + (size_t)bh * 4096 + (size_t)i * 64 + jci * 2;
    s0 = sp[0]; s1 = sp[1];
  }

  __shared__ __align__(16) char lds[90112];

  // named staging registers (rule #20)
  f32x2 ak0a, ak0k, br0b, br0r;  unsigned e0r;   // chunk c = tid
  f32x2 ak1a, ak1k, br1b, br1r;  unsigned e1r;   // chunk c = tid + 512
  f32x4 vv4;

#define SLOAD(gg) { \
  size_t gb_ = (mbase + (size_t)(gg) * SG) * Cdim + cb; \
  { int sub_ = tid >> 5, j_ = tid & 31; \
    size_t a_ = gb_ + (size_t)sub_ * Cdim + j_ * 2; \
    ak0a = *(const f32x2*)(ain + a_);  ak0k = *(const f32x2*)(k + a_); \
    br0b = *(const f32x2*)(bin + a_);  br0r = *(const f32x2*)(r + a_); \
    e0r  = *(const unsigned*)(ew + a_); } \
  { int sub_ = 16 + (tid >> 5), j_ = tid & 31; \
    size_t a_ = gb_ + (size_t)sub_ * Cdim + j_ * 2; \
    ak1a = *(const f32x2*)(ain + a_);  ak1k = *(const f32x2*)(k + a_); \
    br1b = *(const f32x2*)(bin + a_);  br1r = *(const f32x2*)(r + a_); \
    e1r  = *(const unsigned*)(ew + a_); } \
  { int sub_ = tid >> 4, ch_ = (tid & 15) * 4; \
    vv4 = *(const f32x4*)(v + gb_ + (size_t)sub_ * Cdim + ch_); } }

#define SWRITE(slot) { \
  char* b_ = lds + (slot) * 45056; \
  { int sub_ = tid >> 5, j_ = tid & 31; \
    f32x4 t_; t_[0] = ak0a[0]; t_[1] = ak0a[1]; t_[2] = ak0k[0]; t_[3] = ak0k[1]; \
    *(f32x4*)(b_ + sub_ * 512 + j_ * 16) = t_; \
    f32x4 u_; u_[0] = br0b[0]; u_[1] = br0b[1]; u_[2] = br0r[0]; u_[3] = br0r[1]; \
    *(f32x4*)(b_ + 16384 + sub_ * 512 + j_ * 16) = u_; \
    *(unsigned*)(b_ + 40960 + sub_ * 128 + j_ * 4) = e0r; } \
  { int sub_ = 16 + (tid >> 5), j_ = tid & 31; \
    f32x4 t_; t_[0] = ak1a[0]; t_[1] = ak1a[1]; t_[2] = ak1k[0]; t_[3] = ak1k[1]; \
    *(f32x4*)(b_ + sub_ * 512 + j_ * 16) = t_; \
    f32x4 u_; u_[0] = br1b[0]; u_[1] = br1b[1]; u_[2] = br1r[0]; u_[3] = br1r[1]; \
    *(f32x4*)(b_ + 16384 + sub_ * 512 + j_ * 16) = u_; \
    *(unsigned*)(b_ + 40960 + sub_ * 128 + j_ * 4) = e1r; } \
  { int sub_ = tid >> 4, ch_ = (tid & 15) * 4; \
    *(f32x4*)(b_ + 32768 + sub_ * 256 + ch_ * 4) = vv4; } }

  const int NG = Tdim / SG;   // 64
  SLOAD(0)
  SWRITE(0)
  SLOAD(1)
  __syncthreads();

  for (int g = 0; g < NG; ++g) {
    {
      char* b_ = lds + (g & 1) * 45056;
      size_t obase = (mbase + (size_t)g * SG) * Cdim + cb + i;
#pragma unroll
      for (int sub = 0; sub < SG; ++sub) {
        f32x4 akv = *(const f32x4*)(b_ + sub * 512 + jci * 16);
        f32x4 brv = *(const f32x4*)(b_ + 16384 + sub * 512 + jci * 16);
        float vi_ = *(const float*)(b_ + 32768 + sub * 256 + i * 4);
        unsigned e_ = *(const unsigned*)(b_ + 40960 + sub * 128 + jci * 4);
        float p_ = s0 * akv[0] + s1 * akv[1];
        p_ = dpp_red16(p_);
        p_ = sum32(p_);
        float e0_ = b2f((u16)(e_ & 0xFFFFu));
        float e1_ = b2f((u16)(e_ >> 16));
        float sn0_ = s0 * e0_ + p_ * brv[0] + vi_ * akv[2];
        float sn1_ = s1 * e1_ + p_ * brv[1] + vi_ * akv[3];
        s0 = sn0_; s1 = sn1_;
        float oo_ = sn0_ * brv[2] + sn1_ * brv[3];
        oo_ = dpp_red16(oo_);
        oo_ = sum32(oo_);
        if (jci == 0) o[obase + (size_t)sub * Cdim] = oo_;
      }
    }
    __syncthreads();                       // all waves done reading slot g&1
    if (g + 1 < NG) {
      SWRITE((g + 1) & 1)                  // write group g+1 (regs from prev SLOAD)
      if (g + 2 < NG) SLOAD(g + 2)
      __syncthreads();                     // writes visible before compute(g+1)
    }
  }
#undef SLOAD
#undef SWRITE
}

// ---------------- GroupNorm + bonus + gate -> og hi/lo ----------------
__global__ __launch_bounds__(256) void gn_kernel(
    const float* __restrict__ o_raw, const float* __restrict__ r,
    const float* __restrict__ k, const float* __restrict__ v,
    const float* __restrict__ g, const float* __restrict__ rkw,
    const float* __restrict__ ln_w, const float* __restrict__ ln_b,
    u16* __restrict__ og_h, u16* __restrict__ og_l)
{
  int gid = blockIdx.x * 4 + (threadIdx.x >> 6);
  int lane = threadIdx.x & 63;
  int m = gid >> 5, h = gid & 31;
  int c = h * 64 + lane;
  size_t idx = (size_t)m * Cdim + c;

  float ov = o_raw[idx];
  float rv = r[idx], kv = k[idx], vv = v[idx];
  float rk = rv * kv * rkw[c];

  float s1 = ov, s2 = ov * ov, s3 = rk;
#pragma unroll
  for (int off = 32; off; off >>= 1) {
    s1 += __shfl_xor(s1, off);
    s2 += __shfl_xor(s2, off);
    s3 += __shfl_xor(s3, off);
  }
  float mu = s1 * (1.f / 64.f);
  float var = s2 * (1.f / 64.f) - mu * mu;
  float xh = (ov - mu) * rsqrtf(var + 6.4e-4f);   // eps = 1e-5 * 8^2
  float gn = xh * ln_w[c] + ln_b[c];
  float outp = (gn + s3 * vv) * g[idx];
  u16 hh = f2bf(outp);
  og_h[idx] = hh;
  og_l[idx] = f2bf(outp - b2f(hh));
}

// ---------------- host ----------------
extern "C" void kernel_launch(void* const* d_in, const int* in_sizes, int n_in,
                              void* d_out, int out_size, void* d_ws, size_t ws_size,
                              hipStream_t stream) {
  const float* x      = (const float*)d_in[0];
  const float* shiftS = (const float*)d_in[1];
  const float* vfirst = (const float*)d_in[2];
  const float* wkv0   = (const float*)d_in[3];
  const float* x_r = (const float*)d_in[4];
  const float* x_w = (const float*)d_in[5];
  const float* x_k = (const float*)d_in[6];
  const float* x_v = (const float*)d_in[7];
  const float* x_a = (const float*)d_in[8];
  const float* x_g = (const float*)d_in[9];
  const float* w0 = (const float*)d_in[10];
  const float* w1 = (const float*)d_in[11];
  const float* w2 = (const float*)d_in[12];
  const float* a0 = (const float*)d_in[13];
  const float* a1 = (const float*)d_in[14];
  const float* a2 = (const float*)d_in[15];
  const float* v0 = (const float*)d_in[16];
  const float* v1 = (const float*)d_in[17];
  const float* v2 = (const float*)d_in[18];
  const float* g1 = (const float*)d_in[19];
  const float* g2 = (const float*)d_in[20];
  const float* k_k = (const float*)d_in[21];
  const float* k_a = (const float*)d_in[22];
  const float* r_k = (const float*)d_in[23];
  const float* Wr = (const float*)d_in[24];
  const float* Wk = (const float*)d_in[25];
  const float* Wv = (const float*)d_in[26];
  const float* Wo = (const float*)d_in[27];
  const float* ln_w = (const float*)d_in[28];
  const float* ln_b = (const float*)d_in[29];
  (void)in_sizes; (void)n_in;

  const size_t MC = (size_t)Mdim * Cdim;      // 8,388,608
  const size_t CC = (size_t)Cdim * Cdim;
  const size_t SLOT = MC * 2;                 // 16 MiB

  char* cur = (char*)d_ws;
  auto alloc = [&](size_t bytes) -> void* {
    void* p = cur;
    cur += (bytes + 255) & ~(size_t)255;
    return p;
  };

  // X region: 13 slots with liveness-based reuse (all hazards stream-ordered)
  char* X = (char*)alloc(13 * SLOT);
  u16* xr_h = (u16*)(X + 0 * SLOT);
  u16* xr_l = (u16*)(X + 1 * SLOT);
  u16* xk_h = (u16*)(X + 2 * SLOT);
  u16* xk_l = (u16*)(X + 3 * SLOT);
  u16* xv_h = (u16*)(X + 4 * SLOT);
  u16* xv_l = (u16*)(X + 5 * SLOT);
  u16* xw   = (u16*)(X + 6 * SLOT);
  u16* xa   = (u16*)(X + 7 * SLOT);
  u16* xg_h = (u16*)(X + 8 * SLOT);
  u16* xg_l = (u16*)(X + 9 * SLOT);
  // reuse:
  float* r_f32 = (float*)(X + 8 * SLOT);    // S8S9 (xg dead after LoRA-1)
  float* k_f32 = (float*)(X + 0 * SLOT);    // S0S1 (xr dead after r GEMM)
  float* v_f32 = (float*)(X + 2 * SLOT);    // S2S3 (xk dead after k GEMM)
  float* a_f32 = (float*)(X + 10 * SLOT);   // S10S11 (Wk/Wv pairs dead after big GEMMs)
  u16*   ew_bf = (u16*)(X + 12 * SLOT);     // S12 (virgin)
  float* ain_f = (float*)(X + 4 * SLOT);    // S4S5 (xv dead after v GEMM)
  float* bin_f = (float*)(X + 6 * SLOT);    // S6S7 (xw,xa dead after LoRA-1)
  float* o_f32 = (float*)(X + 10 * SLOT);   // S10S11 (a dead after post)
  float* g_f32 = (float*)(X + 6 * SLOT);    // S6S7 (bin dead after scan)
  u16*   og_h  = (u16*)(X + 4 * SLOT);      // S4 (ain dead after scan)
  u16*   og_l  = (u16*)(X + 5 * SLOT);      // S5
  // Wk/Wv split pairs live in S10/S11 during the big GEMMs only (dead before lora2):
  u16* Wk_h = (u16*)(X + 10 * SLOT);
  u16* Wk_l = (u16*)(X + 10 * SLOT + CC * 2);
  u16* Wv_h = (u16*)(X + 11 * SLOT);
  u16* Wv_l = (u16*)(X + 11 * SLOT + CC * 2);

  // W region: one split pair for Wr, reused for Wo at the end
  u16* Wh = (u16*)alloc(CC * 2);
  u16* Wl = (u16*)alloc(CC * 2);

  // L region: LoRA packs + small intermediates
  u16* w1t = (u16*)alloc((size_t)128 * 2048 * 2);
  u16* a1t = (u16*)alloc((size_t)128 * 2048 * 2);
  u16* v1t = (u16*)alloc((size_t)128 * 2048 * 2);
  u16* g1t_h = (u16*)alloc((size_t)128 * 2048 * 2);
  u16* g1t_l = (u16*)alloc((size_t)128 * 2048 * 2);
  u16* w2t = (u16*)alloc((size_t)2048 * 64 * 2);
  u16* a2t = (u16*)alloc((size_t)2048 * 64 * 2);
  u16* v2t = (u16*)alloc((size_t)2048 * 32 * 2);
  u16* g2t_h = (u16*)alloc((size_t)2048 * 128 * 2);
  u16* g2t_l = (u16*)alloc((size_t)2048 * 128 * 2);
  u16* hb_w = (u16*)alloc((size_t)Mdim * 64 * 2);
  u16* hb_a = (u16*)alloc((size_t)Mdim * 64 * 2);
  u16* hb_v = (u16*)alloc((size_t)Mdim * 32 * 2);
  u16* sig_h = (u16*)alloc((size_t)Mdim * 128 * 2);
  u16* sig_l = (u16*)alloc((size_t)Mdim * 128 * 2);

  size_t required = (size_t)(cur - (char*)d_ws);
  if (ws_size < required) {
    fill_kernel<<<(out_size + 255) / 256, 256, 0, stream>>>(
        (float*)d_out, (float)(ws_size >> 20), out_size);
    return;
  }

  // 1) token-shift prep
  prep_kernel<<<(int)(MC / 256), 256, 0, stream>>>(
      x, shiftS, x_r, x_w, x_k, x_v, x_a, x_g,
      xr_h, xr_l, xk_h, xk_l, xv_h, xv_l, xg_h, xg_l, xw, xa);

  // 2) LoRA weight packs (single fused launch)
  pack_all_kernel<<<6400, 256, 0, stream>>>(
      w1, a1, v1, g1, w2, a2, v2, g2,
      w1t, a1t, v1t, g1t_h, g1t_l, w2t, a2t, v2t, g2t_h, g2t_l);

  // 2b) fused cast of Wr/Wk/Wv split pairs (one launch; Wk->S10, Wv->S11)
  cast3_kernel<<<(int)(3 * CC / 256), 256, 0, stream>>>(
      Wr, Wh, Wl, Wk, Wk_h, Wk_l, Wv, Wv_h, Wv_l);

  // 3) LoRA-1: plain fused (w tanh / a / v) + split g sigmoid
  dim3 gL1(Mdim / 128, 1, 3);
  lora1_kernel<<<gL1, 256, 0, stream>>>(xw, xa, xv_h, w1t, a1t, v1t,
                                        hb_w, hb_a, hb_v, 64, 64, 32);
  dim3 gL1g(Mdim / 128, 1);
  gemm_split<1><<<gL1g, 256, 0, stream>>>(xg_h, xg_l, g1t_h, g1t_l,
                                          sig_h, sig_l, 2048, 128, 128);

  // 4) big projections (split, f32 out), back-to-back
  dim3 gBig(Mdim / 128, Cdim / 128);
  gemm_split<0><<<gBig, 256, 0, stream>>>(xr_h, xr_l, Wh, Wl, r_f32, nullptr, Cdim, Cdim, Cdim);
  gemm_split<0><<<gBig, 256, 0, stream>>>(xk_h, xk_l, Wk_h, Wk_l, k_f32, nullptr, Cdim, Cdim, Cdim);
  gemm_split<0><<<gBig, 256, 0, stream>>>(xv_h, xv_l, Wv_h, Wv_l, v_f32, nullptr, Cdim, Cdim, Cdim);

  // 5) LoRA-2 fused: ew (bf16), a (f32, overwrites Wk/Wv pairs - dead), vmix (in-place)
  dim3 gL2(Mdim / 128, Cdim / 128, 3);
  lora2_kernel<<<gL2, 256, 0, stream>>>(hb_w, hb_a, hb_v, w2t, a2t, v2t,
                                        ew_bf, a_f32, v_f32, w0, a0, v0, vfirst);

  // 6) post: kk-norm -> ain/bin, k-scale in-place
  post_kernel<<<(Mdim * Hdim) / 4, 256, 0, stream>>>(
      k_f32, a_f32, k_k, k_a, ain_f, bin_f);

  // 7) scan v15 (256 blocks x 8 waves, builtin-permlane cross-half reduce)
  scan_kernel<<<256, 512, 0, stream>>>(
      r_f32, ew_bf, k_f32, v_f32, ain_f, bin_f, wkv0, o_f32);

  // 8) LoRA-2 g (split, f32) — after scan so bin slots are free
  gemm_split<0><<<gBig, 256, 0, stream>>>(sig_h, sig_l, g2t_h, g2t_l,
                                          g_f32, nullptr, 128, Cdim, Cdim);

  // 9) GroupNorm + bonus + gate -> og hi/lo
  gn_kernel<<<(Mdim * Hdim) / 4, 256, 0, stream>>>(
      o_f32, r_f32, k_f32, v_f32, g_f32, r_k, ln_w, ln_b, og_h, og_l);

  // 10) output projection (split; Wr pair dead -> reuse Wh/Wl for Wo)
  cast_split_kernel<<<(int)(CC / 256), 256, 0, stream>>>(Wo, Wh, Wl);
  gemm_split<0><<<gBig, 256, 0, stream>>>(og_h, og_l, Wh, Wl,
                                          (float*)d_out, nullptr, Cdim, Cdim, Cdim);
}

// Round 21
// 995.295 us; speedup vs baseline: 1.0963x; 1.0963x over previous
//
#include <hip/hip_runtime.h>

#define Bdim 2
#define Tdim 2048
#define Cdim 2048
#define Hdim 32
#define Mdim (Bdim*Tdim)   // 4096

typedef unsigned short u16;
typedef short bf16x8 __attribute__((ext_vector_type(8)));
typedef float f32x2 __attribute__((ext_vector_type(2)));
typedef float f32x4 __attribute__((ext_vector_type(4)));

__device__ __forceinline__ u16 f2bf(float f) {
  unsigned u = __float_as_uint(f);
  u = (u + 0x7FFFu + ((u >> 16) & 1u)) >> 16;
  return (u16)u;
}
__device__ __forceinline__ float b2f(u16 h) {
  return __uint_as_float(((unsigned)h) << 16);
}
__device__ __forceinline__ float sigf(float x) { return 1.f / (1.f + expf(-x)); }

// async global->LDS, 16B per lane; LDS dest = wave-uniform base + lane*16
__device__ __forceinline__ void gld16(const u16* g, u16* l) {
  __builtin_amdgcn_global_load_lds(
      (const __attribute__((address_space(1))) unsigned int*)g,
      (__attribute__((address_space(3))) unsigned int*)l, 16, 0, 0);
}

// sum within each 16-lane DPP row via rotations: row_ror:8,4,2,1.
__device__ __forceinline__ float dpp_red16(float x) {
  int t = __builtin_amdgcn_mov_dpp(__float_as_int(x), 0x128, 0xF, 0xF, true);
  x += __int_as_float(t);
  t = __builtin_amdgcn_mov_dpp(__float_as_int(x), 0x124, 0xF, 0xF, true);
  x += __int_as_float(t);
  t = __builtin_amdgcn_mov_dpp(__float_as_int(x), 0x122, 0xF, 0xF, true);
  x += __int_as_float(t);
  t = __builtin_amdgcn_mov_dpp(__float_as_int(x), 0x121, 0xF, 0xF, true);
  x += __int_as_float(t);
  return x;
}

// full cross-half (lane^32) SUM via permlane32_swap builtin (R19-proven).
__device__ __forceinline__ float sum32(float x) {
#if __has_builtin(__builtin_amdgcn_permlane32_swap)
  typedef int int2v __attribute__((ext_vector_type(2)));
  int2v res = __builtin_amdgcn_permlane32_swap(__float_as_int(x), __float_as_int(x), false, false);
  return __int_as_float(res[0]) + __int_as_float(res[1]);
#else
  return x + __shfl_xor(x, 32);
#endif
}

// ---------------- diagnostic fill ----------------
__global__ __launch_bounds__(256) void fill_kernel(float* __restrict__ out, float v, int n) {
  int i = blockIdx.x * 256 + threadIdx.x;
  if (i < n) out[i] = v;
}

// ---------------- prep: token-shift mix; r/k/v/g as hi/lo split, w/a single ----------------
__global__ __launch_bounds__(256) void prep_kernel(
    const float* __restrict__ x, const float* __restrict__ shift,
    const float* __restrict__ mr, const float* __restrict__ mw,
    const float* __restrict__ mk, const float* __restrict__ mv,
    const float* __restrict__ ma, const float* __restrict__ mg,
    u16* __restrict__ xr_h, u16* __restrict__ xr_l,
    u16* __restrict__ xk_h, u16* __restrict__ xk_l,
    u16* __restrict__ xv_h, u16* __restrict__ xv_l,
    u16* __restrict__ xg_h, u16* __restrict__ xg_l,
    u16* __restrict__ xw, u16* __restrict__ xa)
{
  size_t idx = (size_t)blockIdx.x * 256 + threadIdx.x;  // < M*C
  int c = (int)(idx & (Cdim - 1));
  size_t row = idx >> 11;
  int t = (int)(row & (Tdim - 1));
  int b = (int)(row >> 11);
  float xc = x[idx];
  float xp = (t == 0) ? shift[(size_t)b * Cdim + c] : x[idx - Cdim];
  float xx = xp - xc;

  float vr = xc + xx * mr[c];
  u16 hr = f2bf(vr); xr_h[idx] = hr; xr_l[idx] = f2bf(vr - b2f(hr));
  float vk = xc + xx * mk[c];
  u16 hk = f2bf(vk); xk_h[idx] = hk; xk_l[idx] = f2bf(vk - b2f(hk));
  float vv = xc + xx * mv[c];
  u16 hv = f2bf(vv); xv_h[idx] = hv; xv_l[idx] = f2bf(vv - b2f(hv));
  float vg = xc + xx * mg[c];
  u16 hg = f2bf(vg); xg_h[idx] = hg; xg_l[idx] = f2bf(vg - b2f(hg));

  xw[idx] = f2bf(xc + xx * mw[c]);
  xa[idx] = f2bf(xc + xx * ma[c]);
}

// ---------------- weight packing ----------------
__global__ __launch_bounds__(256) void cast_split_kernel(
    const float* __restrict__ src, u16* __restrict__ hi, u16* __restrict__ lo)
{
  size_t i = (size_t)blockIdx.x * 256 + threadIdx.x;
  float v = src[i];
  u16 h = f2bf(v);
  hi[i] = h;
  lo[i] = f2bf(v - b2f(h));
}

// fused 3-weight split cast: Wr, Wk, Wv in one launch (partitioned by blockIdx).
__global__ __launch_bounds__(256) void cast3_kernel(
    const float* __restrict__ Wr, u16* __restrict__ rh, u16* __restrict__ rl,
    const float* __restrict__ Wk, u16* __restrict__ kh, u16* __restrict__ kl,
    const float* __restrict__ Wv, u16* __restrict__ vh, u16* __restrict__ vl)
{
  const size_t NB = (size_t)Cdim * Cdim / 256;
  size_t bid = blockIdx.x;
  const float* src; u16* hi; u16* lo;
  if (bid < NB)            { src = Wr; hi = rh; lo = rl; }
  else if (bid < 2 * NB)   { src = Wk; hi = kh; lo = kl; bid -= NB; }
  else                     { src = Wv; hi = vh; lo = vl; bid -= 2 * NB; }
  size_t i = bid * 256 + threadIdx.x;
  float v = src[i];
  u16 h = f2bf(v);
  hi[i] = h;
  lo[i] = f2bf(v - b2f(h));
}

// fused LoRA weight packs: 8 transposes in one launch, partitioned by blockIdx.
__global__ __launch_bounds__(256) void pack_all_kernel(
    const float* __restrict__ w1, const float* __restrict__ a1,
    const float* __restrict__ v1, const float* __restrict__ g1,
    const float* __restrict__ w2, const float* __restrict__ a2,
    const float* __restrict__ v2, const float* __restrict__ g2,
    u16* __restrict__ w1t, u16* __restrict__ a1t, u16* __restrict__ v1t,
    u16* __restrict__ g1t_h, u16* __restrict__ g1t_l,
    u16* __restrict__ w2t, u16* __restrict__ a2t, u16* __restrict__ v2t,
    u16* __restrict__ g2t_h, u16* __restrict__ g2t_l)
{
  int bid = blockIdx.x;
  const float* src; u16* dh; u16* dl = nullptr;
  int K, Nsrc; size_t idx0;
  if (bid < 1024)      { src = w1; dh = w1t;   K = 2048; Nsrc = 64;   idx0 = (size_t)bid * 256; }
  else if (bid < 2048) { src = a1; dh = a1t;   K = 2048; Nsrc = 64;   idx0 = (size_t)(bid - 1024) * 256; }
  else if (bid < 3072) { src = v1; dh = v1t;   K = 2048; Nsrc = 32;   idx0 = (size_t)(bid - 2048) * 256; }
  else if (bid < 4096) { src = g1; dh = g1t_h; dl = g1t_l; K = 2048; Nsrc = 128; idx0 = (size_t)(bid - 3072) * 256; }
  else if (bid < 4608) { src = w2; dh = w2t;   K = 64;   Nsrc = 2048; idx0 = (size_t)(bid - 4096) * 256; }
  else if (bid < 5120) { src = a2; dh = a2t;   K = 64;   Nsrc = 2048; idx0 = (size_t)(bid - 4608) * 256; }
  else if (bid < 5376) { src = v2; dh = v2t;   K = 32;   Nsrc = 2048; idx0 = (size_t)(bid - 5120) * 256; }
  else                 { src = g2; dh = g2t_h; dl = g2t_l; K = 128;  Nsrc = 2048; idx0 = (size_t)(bid - 5376) * 256; }
  size_t idx = idx0 + threadIdx.x;
  int n = (int)(idx / K);
  int kk = (int)(idx - (size_t)n * K);
  float v = (n < Nsrc) ? src[(size_t)kk * Nsrc + n] : 0.f;
  u16 h = f2bf(v);
  dh[idx] = h;
  if (dl) dl[idx] = f2bf(v - b2f(h));
}

// LDS bank swizzle (both-sides, rule 21): content[row][slot] = global[row][slot^(row&3)]

// ================= plain bf16 GEMM body (smem-pointer), 128x128, BK=32, 2-phase =================
// EP: 2 none/tanh(act)->bf16 | 3 ew=bf16(0.6065*sig(bias[n]+x))
//     4 a=f32 sig(bias[n]+x) | 5 vmix: f32 out = aux1 + (aux2-aux1)*sig(bias[n]+x)
// smem usage: 32768 bytes.
template <int EP>
__device__ __forceinline__ void gemm_plain_body(
    char* smem, const u16* __restrict__ A, const u16* __restrict__ B, void* __restrict__ Cv,
    const float* __restrict__ bias, const float* __restrict__ aux1,
    const float* __restrict__ aux2, int K, int Nact, int ldC, int act)
{
  u16 (*As)[128][32] = (u16 (*)[128][32])smem;
  u16 (*Bs)[128][32] = (u16 (*)[128][32])(smem + 16384);
  int tid = threadIdx.x;
  int lane = tid & 63, wave = tid >> 6;
  int wm = wave >> 1, wn = wave & 1;
  int bm = blockIdx.x * 128, bn = blockIdx.y * 128;
  f32x4 zero = {0.f, 0.f, 0.f, 0.f};
  f32x4 acc[4][4];
#pragma unroll
  for (int i = 0; i < 4; i++)
#pragma unroll
    for (int j = 0; j < 4; j++) acc[i][j] = zero;
  int srow = tid >> 2;
  int sslot = tid & 3;
  int scol = (sslot ^ (srow & 3)) << 3;     // swizzled source col (u16)
  int dcol = sslot << 3;                    // linear LDS dest col
  const u16* gA  = A + (size_t)(bm + srow) * K + scol;
  const u16* gA2 = A + (size_t)(bm + 64 + srow) * K + scol;
  const u16* gB  = B + (size_t)(bn + srow) * K + scol;
  const u16* gB2 = B + (size_t)(bn + 64 + srow) * K + scol;
  int fr = lane & 15;
  int fk = ((lane >> 4) << 3) ^ ((fr & 3) << 3);   // swizzled fragment col

#define STAGEP(buf, kk) { \
  gld16(gA + (kk), &As[buf][srow][dcol]); \
  gld16(gA2 + (kk), &As[buf][64 + srow][dcol]); \
  gld16(gB + (kk), &Bs[buf][srow][dcol]); \
  gld16(gB2 + (kk), &Bs[buf][64 + srow][dcol]); }

  STAGEP(0, 0)
  __syncthreads();
  int cur = 0;
  for (int k0 = 0; k0 < K; k0 += 32) {
    if (k0 + 32 < K) STAGEP(cur ^ 1, k0 + 32)
    bf16x8 af[4], bfv[4];
#pragma unroll
    for (int i = 0; i < 4; i++) af[i] = *(const bf16x8*)&As[cur][wm * 64 + i * 16 + fr][fk];
#pragma unroll
    for (int j = 0; j < 4; j++) bfv[j] = *(const bf16x8*)&Bs[cur][wn * 64 + j * 16 + fr][fk];
#pragma unroll
    for (int i = 0; i < 4; i++)
#pragma unroll
      for (int j = 0; j < 4; j++)
        acc[i][j] = __builtin_amdgcn_mfma_f32_16x16x32_bf16(af[i], bfv[j], acc[i][j], 0, 0, 0);
    __syncthreads();   // drains vmcnt (stage) + lgkmcnt; next tile ready
    cur ^= 1;
  }
#undef STAGEP
  int rb = (lane >> 4) << 2;   // C/D: col=lane&15, row=(lane>>4)*4+reg [m89/m91]
  int cc = lane & 15;
#pragma unroll
  for (int i = 0; i < 4; i++) {
    int mm = bm + wm * 64 + i * 16 + rb;
#pragma unroll
    for (int j = 0; j < 4; j++) {
      int nn = bn + wn * 64 + j * 16 + cc;
      if (nn < Nact) {
#pragma unroll
        for (int r = 0; r < 4; r++) {
          float val = acc[i][j][r];
          size_t oidx = (size_t)(mm + r) * ldC + nn;
          if (EP == 2) {
            if (act == 1) val = tanhf(val);
            ((u16*)Cv)[oidx] = f2bf(val);
          }
          else if (EP == 3) ((u16*)Cv)[oidx] = f2bf(0.60653065971f * sigf(bias[nn] + val));
          else if (EP == 4) ((float*)Cv)[oidx] = sigf(bias[nn] + val);
          else if (EP == 5) {
            float vraw = aux1[oidx], vf = aux2[oidx];
            ((float*)Cv)[oidx] = vraw + (vf - vraw) * sigf(bias[nn] + val);
          }
        }
      }
    }
  }
}

// ================= split-bf16 GEMM body (smem-pointer): D = Ah*Bh + Ah*Bl + Al*Bh =================
// smem usage: 65536 bytes. EP: 0 f32 | 1 sigmoid -> hi/lo pair
template <int EP>
__device__ __forceinline__ void gemm_split_body(
    char* smem, const u16* __restrict__ Ah, const u16* __restrict__ Al,
    const u16* __restrict__ Bh, const u16* __restrict__ Bl,
    void* __restrict__ C1, u16* __restrict__ C2, int K, int Nact, int ldC)
{
  u16 (*Ash)[128][32] = (u16 (*)[128][32])smem;
  u16 (*Asl)[128][32] = (u16 (*)[128][32])(smem + 16384);
  u16 (*Bsh)[128][32] = (u16 (*)[128][32])(smem + 32768);
  u16 (*Bsl)[128][32] = (u16 (*)[128][32])(smem + 49152);
  int tid = threadIdx.x;
  int lane = tid & 63, wave = tid >> 6;
  int wm = wave >> 1, wn = wave & 1;
  int bm = blockIdx.x * 128, bn = blockIdx.y * 128;
  f32x4 zero = {0.f, 0.f, 0.f, 0.f};
  f32x4 acc[4][4];
#pragma unroll
  for (int i = 0; i < 4; i++)
#pragma unroll
    for (int j = 0; j < 4; j++) acc[i][j] = zero;
  int srow = tid >> 2;
  int sslot = tid & 3;
  int scol = (sslot ^ (srow & 3)) << 3;
  int dcol = sslot << 3;
  size_t ga  = (size_t)(bm + srow) * K + scol;
  size_t ga2 = (size_t)(bm + 64 + srow) * K + scol;
  size_t gb  = (size_t)(bn + srow) * K + scol;
  size_t gb2 = (size_t)(bn + 64 + srow) * K + scol;
  int fr = lane & 15;
  int fk = ((lane >> 4) << 3) ^ ((fr & 3) << 3);

#define STAGES(buf, kk) { \
  gld16(Ah + ga + (kk), &Ash[buf][srow][dcol]); \
  gld16(Ah + ga2 + (kk), &Ash[buf][64 + srow][dcol]); \
  gld16(Al + ga + (kk), &Asl[buf][srow][dcol]); \
  gld16(Al + ga2 + (kk), &Asl[buf][64 + srow][dcol]); \
  gld16(Bh + gb + (kk), &Bsh[buf][srow][dcol]); \
  gld16(Bh + gb2 + (kk), &Bsh[buf][64 + srow][dcol]); \
  gld16(Bl + gb + (kk), &Bsl[buf][srow][dcol]); \
  gld16(Bl + gb2 + (kk), &Bsl[buf][64 + srow][dcol]); }

  STAGES(0, 0)
  __syncthreads();
  int cur = 0;
  for (int k0 = 0; k0 < K; k0 += 32) {
    if (k0 + 32 < K) STAGES(cur ^ 1, k0 + 32)
    bf16x8 fah[4], fal[4], fbh[4], fbl[4];
#pragma unroll
    for (int i = 0; i < 4; i++) {
      fah[i] = *(const bf16x8*)&Ash[cur][wm * 64 + i * 16 + fr][fk];
      fal[i] = *(const bf16x8*)&Asl[cur][wm * 64 + i * 16 + fr][fk];
    }
#pragma unroll
    for (int j = 0; j < 4; j++) {
      fbh[j] = *(const bf16x8*)&Bsh[cur][wn * 64 + j * 16 + fr][fk];
      fbl[j] = *(const bf16x8*)&Bsl[cur][wn * 64 + j * 16 + fr][fk];
    }
#pragma unroll
    for (int i = 0; i < 4; i++)
#pragma unroll
      for (int j = 0; j < 4; j++) {
        acc[i][j] = __builtin_amdgcn_mfma_f32_16x16x32_bf16(fah[i], fbh[j], acc[i][j], 0, 0, 0);
        acc[i][j] = __builtin_amdgcn_mfma_f32_16x16x32_bf16(fah[i], fbl[j], acc[i][j], 0, 0, 0);
        acc[i][j] = __builtin_amdgcn_mfma_f32_16x16x32_bf16(fal[i], fbh[j], acc[i][j], 0, 0, 0);
      }
    __syncthreads();
    cur ^= 1;
  }
#undef STAGES
  int rb = (lane >> 4) << 2;
  int cc = lane & 15;
#pragma unroll
  for (int i = 0; i < 4; i++) {
    int mm = bm + wm * 64 + i * 16 + rb;
#pragma unroll
    for (int j = 0; j < 4; j++) {
      int nn = bn + wn * 64 + j * 16 + cc;
      if (nn < Nact) {
#pragma unroll
        for (int r = 0; r < 4; r++) {
          float val = acc[i][j][r];
          size_t oidx = (size_t)(mm + r) * ldC + nn;
          if (EP == 0) ((float*)C1)[oidx] = val;
          else {
            float s = sigf(val);
            u16 h = f2bf(s);
            ((u16*)C1)[oidx] = h;
            C2[oidx] = f2bf(s - b2f(h));
          }
        }
      }
    }
  }
}

// ---------------- wrappers ----------------
template <int EP>
__global__ __launch_bounds__(256) void gemm_split(
    const u16* Ah, const u16* Al, const u16* Bh, const u16* Bl,
    void* C1, u16* C2, int K, int Nact, int ldC)
{
  __shared__ __align__(16) char smem[65536];
  gemm_split_body<EP>(smem, Ah, Al, Bh, Bl, C1, C2, K, Nact, ldC);
}

// merged LoRA-1 (z=0 w tanh, z=1 a, z=2 v) + g1 split sigmoid (z=3) — concurrent
__global__ __launch_bounds__(256) void lora1g_kernel(
    const u16* A0, const u16* A1, const u16* A2,
    const u16* B0, const u16* B1, const u16* B2,
    u16* C0, u16* C1, u16* C2,
    const u16* Agh, const u16* Agl, const u16* Bgh, const u16* Bgl,
    u16* Cgh, u16* Cgl)
{
  __shared__ __align__(16) char smem[65536];
  int z = blockIdx.z;
  if (z < 3) {
    const u16* A = (z == 0) ? A0 : (z == 1) ? A1 : A2;
    const u16* B = (z == 0) ? B0 : (z == 1) ? B1 : B2;
    u16* C      = (z == 0) ? C0 : (z == 1) ? C1 : C2;
    int Nact    = (z == 0) ? 64 : (z == 1) ? 64 : 32;
    int act     = (z == 0) ? 1 : 0;
    gemm_plain_body<2>(smem, A, B, C, nullptr, nullptr, nullptr, 2048, Nact, Nact, act);
  } else {
    gemm_split_body<1>(smem, Agh, Agl, Bgh, Bgl, Cgh, Cgl, 2048, 128, 128);
  }
}

// merged k+v projections (z=0: k, z=1: v) — disjoint buffers, concurrent
__global__ __launch_bounds__(256) void kv2_kernel(
    const u16* Akh, const u16* Akl, const u16* Bkh, const u16* Bkl, float* Ck,
    const u16* Avh, const u16* Avl, const u16* Bvh, const u16* Bvl, float* Cv2)
{
  __shared__ __align__(16) char smem[65536];
  if (blockIdx.z == 0)
    gemm_split_body<0>(smem, Akh, Akl, Bkh, Bkl, Ck, nullptr, Cdim, Cdim, Cdim);
  else
    gemm_split_body<0>(smem, Avh, Avl, Bvh, Bvl, Cv2, nullptr, Cdim, Cdim, Cdim);
}

// fused LoRA-2 (z: 0=ew EP3 K=64, 1=a EP4 K=64, 2=vmix EP5 K=32)
__global__ __launch_bounds__(256) void lora2_kernel(
    const u16* Aw, const u16* Aa, const u16* Av,
    const u16* Bw, const u16* Ba, const u16* Bv,
    u16* Cw, float* Ca, float* Cv,
    const float* w0, const float* a0, const float* v0,
    const float* vfirst)
{
  __shared__ __align__(16) char smem[32768];
  int z = blockIdx.z;
  if (z == 0)
    gemm_plain_body<3>(smem, Aw, Bw, Cw, w0, nullptr, nullptr, 64, Cdim, Cdim, 0);
  else if (z == 1)
    gemm_plain_body<4>(smem, Aa, Ba, Ca, a0, nullptr, nullptr, 64, Cdim, Cdim, 0);
  else
    gemm_plain_body<5>(smem, Av, Bv, Cv, v0, Cv, vfirst, 32, Cdim, Cdim, 0);
}

// ---------------- post: kk-norm + ain/bin + k-scale (one wave per (m,h)) ----------------
__global__ __launch_bounds__(256) void post_kernel(
    float* __restrict__ k, const float* __restrict__ a,
    const float* __restrict__ k_k, const float* __restrict__ k_a,
    float* __restrict__ ain, float* __restrict__ bin)
{
  int gid = blockIdx.x * 4 + (threadIdx.x >> 6);
  int lane = threadIdx.x & 63;
  int m = gid >> 5, h = gid & 31;
  int c = h * 64 + lane;
  size_t idx = (size_t)m * Cdim + c;

  float kr = k[idx];
  float av = a[idx];

  float kkv = kr * k_k[c];
  float ss = kkv * kkv;
#pragma unroll
  for (int off = 32; off; off >>= 1) ss += __shfl_xor(ss, off);
  float kkn = kkv / fmaxf(sqrtf(ss), 1e-12f);

  ain[idx] = -kkn;
  bin[idx] = kkn * av;
  k[idx] = kr * (1.f + (av - 1.f) * k_a[c]);
}

// ---------------- scan v15: LDS-shared 8-wave blocks + builtin permlane reduce ----------------
#define SG 32
__global__ __launch_bounds__(512) void scan_kernel(
    const float* __restrict__ r, const u16* __restrict__ ew,
    const float* __restrict__ k, const float* __restrict__ v,
    const float* __restrict__ ain, const float* __restrict__ bin,
    const float* __restrict__ S0, float* __restrict__ o)
{
  int bh = blockIdx.x & 63;
  int q4 = blockIdx.x >> 6;       // 0..3
  int tid = threadIdx.x;
  int wv = tid >> 6;              // 0..7
  int lane = tid & 63;
  int jci = (lane & 15) | ((lane >> 1) & 16);  // j-chunk 0..31
  int lr = (lane >> 4) & 1;                    // row bit
  int i = q4 * 16 + wv * 2 + lr;  // channel row 0..63
  int cb = (bh & 31) * 64;        // channel base
  size_t mbase = (size_t)(bh >> 5) * Tdim;   // row base in [M][C]

  float s0, s1;
  {
    const float* sp = S0 + (size_t)bh * 4096 + (size_t)i * 64 + jci * 2;
    s0 = sp[0]; s1 = sp[1];
  }

  __shared__ __align__(16) char lds[90112];

  f32x2 ak0a, ak0k, br0b, br0r;  unsigned e0r;
  f32x2 ak1a, ak1k, br1b, br1r;  unsigned e1r;
  f32x4 vv4;

#define SLOAD(gg) { \
  size_t gb_ = (mbase + (size_t)(gg) * SG) * Cdim + cb; \
  { int sub_ = tid >> 5, j_ = tid & 31; \
    size_t a_ = gb_ + (size_t)sub_ * Cdim + j_ * 2; \
    ak0a = *(const f32x2*)(ain + a_);  ak0k = *(const f32x2*)(k + a_); \
    br0b = *(const f32x2*)(bin + a_);  br0r = *(const f32x2*)(r + a_); \
    e0r  = *(const unsigned*)(ew + a_); } \
  { int sub_ = 16 + (tid >> 5), j_ = tid & 31; \
    size_t a_ = gb_ + (size_t)sub_ * Cdim + j_ * 2; \
    ak1a = *(const f32x2*)(ain + a_);  ak1k = *(const f32x2*)(k + a_); \
    br1b = *(const f32x2*)(bin + a_);  br1r = *(const f32x2*)(r + a_); \
    e1r  = *(const unsigned*)(ew + a_); } \
  { int sub_ = tid >> 4, ch_ = (tid & 15) * 4; \
    vv4 = *(const f32x4*)(v + gb_ + (size_t)sub_ * Cdim + ch_); } }

#define SWRITE(slot) { \
  char* b_ = lds + (slot) * 45056; \
  { int sub_ = tid >> 5, j_ = tid & 31; \
    f32x4 t_; t_[0] = ak0a[0]; t_[1] = ak0a[1]; t_[2] = ak0k[0]; t_[3] = ak0k[1]; \
    *(f32x4*)(b_ + sub_ * 512 + j_ * 16) = t_; \
    f32x4 u_; u_[0] = br0b[0]; u_[1] = br0b[1]; u_[2] = br0r[0]; u_[3] = br0r[1]; \
    *(f32x4*)(b_ + 16384 + sub_ * 512 + j_ * 16) = u_; \
    *(unsigned*)(b_ + 40960 + sub_ * 128 + j_ * 4) = e0r; } \
  { int sub_ = 16 + (tid >> 5), j_ = tid & 31; \
    f32x4 t_; t_[0] = ak1a[0]; t_[1] = ak1a[1]; t_[2] = ak1k[0]; t_[3] = ak1k[1]; \
    *(f32x4*)(b_ + sub_ * 512 + j_ * 16) = t_; \
    f32x4 u_; u_[0] = br1b[0]; u_[1] = br1b[1]; u_[2] = br1r[0]; u_[3] = br1r[1]; \
    *(f32x4*)(b_ + 16384 + sub_ * 512 + j_ * 16) = u_; \
    *(unsigned*)(b_ + 40960 + sub_ * 128 + j_ * 4) = e1r; } \
  { int sub_ = tid >> 4, ch_ = (tid & 15) * 4; \
    *(f32x4*)(b_ + 32768 + sub_ * 256 + ch_ * 4) = vv4; } }

  const int NG = Tdim / SG;   // 64
  SLOAD(0)
  SWRITE(0)
  SLOAD(1)
  __syncthreads();

  for (int g = 0; g < NG; ++g) {
    {
      char* b_ = lds + (g & 1) * 45056;
      size_t obase = (mbase + (size_t)g * SG) * Cdim + cb + i;
#pragma unroll
      for (int sub = 0; sub < SG; ++sub) {
        f32x4 akv = *(const f32x4*)(b_ + sub * 512 + jci * 16);
        f32x4 brv = *(const f32x4*)(b_ + 16384 + sub * 512 + jci * 16);
        float vi_ = *(const float*)(b_ + 32768 + sub * 256 + i * 4);
        unsigned e_ = *(const unsigned*)(b_ + 40960 + sub * 128 + jci * 4);
        float p_ = s0 * akv[0] + s1 * akv[1];
        p_ = dpp_red16(p_);
        p_ = sum32(p_);
        float e0_ = b2f((u16)(e_ & 0xFFFFu));
        float e1_ = b2f((u16)(e_ >> 16));
        float sn0_ = s0 * e0_ + p_ * brv[0] + vi_ * akv[2];
        float sn1_ = s1 * e1_ + p_ * brv[1] + vi_ * akv[3];
        s0 = sn0_; s1 = sn1_;
        float oo_ = sn0_ * brv[2] + sn1_ * brv[3];
        oo_ = dpp_red16(oo_);
        oo_ = sum32(oo_);
        if (jci == 0) o[obase + (size_t)sub * Cdim] = oo_;
      }
    }
    __syncthreads();
    if (g + 1 < NG) {
      SWRITE((g + 1) & 1)
      if (g + 2 < NG) SLOAD(g + 2)
      __syncthreads();
    }
  }
#undef SLOAD
#undef SWRITE
}

// ---------------- GroupNorm + bonus + gate -> og hi/lo ----------------
__global__ __launch_bounds__(256) void gn_kernel(
    const float* __restrict__ o_raw, const float* __restrict__ r,
    const float* __restrict__ k, const float* __restrict__ v,
    const float* __restrict__ g, const float* __restrict__ rkw,
    const float* __restrict__ ln_w, const float* __restrict__ ln_b,
    u16* __restrict__ og_h, u16* __restrict__ og_l)
{
  int gid = blockIdx.x * 4 + (threadIdx.x >> 6);
  int lane = threadIdx.x & 63;
  int m = gid >> 5, h = gid & 31;
  int c = h * 64 + lane;
  size_t idx = (size_t)m * Cdim + c;

  float ov = o_raw[idx];
  float rv = r[idx], kv = k[idx], vv = v[idx];
  float rk = rv * kv * rkw[c];

  float s1 = ov, s2 = ov * ov, s3 = rk;
#pragma unroll
  for (int off = 32; off; off >>= 1) {
    s1 += __shfl_xor(s1, off);
    s2 += __shfl_xor(s2, off);
    s3 += __shfl_xor(s3, off);
  }
  float mu = s1 * (1.f / 64.f);
  float var = s2 * (1.f / 64.f) - mu * mu;
  float xh = (ov - mu) * rsqrtf(var + 6.4e-4f);   // eps = 1e-5 * 8^2
  float gn = xh * ln_w[c] + ln_b[c];
  float outp = (gn + s3 * vv) * g[idx];
  u16 hh = f2bf(outp);
  og_h[idx] = hh;
  og_l[idx] = f2bf(outp - b2f(hh));
}

// ---------------- host ----------------
extern "C" void kernel_launch(void* const* d_in, const int* in_sizes, int n_in,
                              void* d_out, int out_size, void* d_ws, size_t ws_size,
                              hipStream_t stream) {
  const float* x      = (const float*)d_in[0];
  const float* shiftS = (const float*)d_in[1];
  const float* vfirst = (const float*)d_in[2];
  const float* wkv0   = (const float*)d_in[3];
  const float* x_r = (const float*)d_in[4];
  const float* x_w = (const float*)d_in[5];
  const float* x_k = (const float*)d_in[6];
  const float* x_v = (const float*)d_in[7];
  const float* x_a = (const float*)d_in[8];
  const float* x_g = (const float*)d_in[9];
  const float* w0 = (const float*)d_in[10];
  const float* w1 = (const float*)d_in[11];
  const float* w2 = (const float*)d_in[12];
  const float* a0 = (const float*)d_in[13];
  const float* a1 = (const float*)d_in[14];
  const float* a2 = (const float*)d_in[15];
  const float* v0 = (const float*)d_in[16];
  const float* v1 = (const float*)d_in[17];
  const float* v2 = (const float*)d_in[18];
  const float* g1 = (const float*)d_in[19];
  const float* g2 = (const float*)d_in[20];
  const float* k_k = (const float*)d_in[21];
  const float* k_a = (const float*)d_in[22];
  const float* r_k = (const float*)d_in[23];
  const float* Wr = (const float*)d_in[24];
  const float* Wk = (const float*)d_in[25];
  const float* Wv = (const float*)d_in[26];
  const float* Wo = (const float*)d_in[27];
  const float* ln_w = (const float*)d_in[28];
  const float* ln_b = (const float*)d_in[29];
  (void)in_sizes; (void)n_in;

  const size_t MC = (size_t)Mdim * Cdim;      // 8,388,608
  const size_t CC = (size_t)Cdim * Cdim;
  const size_t SLOT = MC * 2;                 // 16 MiB

  char* cur = (char*)d_ws;
  auto alloc = [&](size_t bytes) -> void* {
    void* p = cur;
    cur += (bytes + 255) & ~(size_t)255;
    return p;
  };

  // X region: 13 slots, liveness-based reuse (all hazards stream-ordered).
  // Phase plan: prep writes S0..S9; lora1g consumes S4(xv_h),S6,S7,S8,S9;
  // r GEMM: S0S1 x Wh/Wl -> S8S9; kv2: z0 S2S3 x S10 -> S0S1, z1 S4S5 x S11 -> S6S7
  // (disjoint read/write sets); lora2: ew->S12, a->S10S11, vmix in-place S6S7;
  // post: ain->S4S5 (xv dead), bin->S2S3 (xk dead); scan -> o S10S11;
  // g GEMM -> S2S3 (bin dead); gn -> og S4/S5 (ain dead).
  char* X = (char*)alloc(13 * SLOT);
  u16* xr_h = (u16*)(X + 0 * SLOT);
  u16* xr_l = (u16*)(X + 1 * SLOT);
  u16* xk_h = (u16*)(X + 2 * SLOT);
  u16* xk_l = (u16*)(X + 3 * SLOT);
  u16* xv_h = (u16*)(X + 4 * SLOT);
  u16* xv_l = (u16*)(X + 5 * SLOT);
  u16* xw   = (u16*)(X + 6 * SLOT);
  u16* xa   = (u16*)(X + 7 * SLOT);
  u16* xg_h = (u16*)(X + 8 * SLOT);
  u16* xg_l = (u16*)(X + 9 * SLOT);
  float* r_f32 = (float*)(X + 8 * SLOT);    // S8S9 (xg dead after lora1g)
  float* k_f32 = (float*)(X + 0 * SLOT);    // S0S1 (xr dead after r GEMM)
  float* v_f32 = (float*)(X + 6 * SLOT);    // S6S7 (xw,xa dead after lora1g)
  float* a_f32 = (float*)(X + 10 * SLOT);   // S10S11 (Wk/Wv pairs dead after kv2)
  u16*   ew_bf = (u16*)(X + 12 * SLOT);     // S12
  float* ain_f = (float*)(X + 4 * SLOT);    // S4S5 (xv dead after kv2)
  float* bin_f = (float*)(X + 2 * SLOT);    // S2S3 (xk dead after kv2)
  float* o_f32 = (float*)(X + 10 * SLOT);   // S10S11 (a dead after post)
  float* g_f32 = (float*)(X + 2 * SLOT);    // S2S3 (bin dead after scan)
  u16*   og_h  = (u16*)(X + 4 * SLOT);      // S4 (ain dead after scan)
  u16*   og_l  = (u16*)(X + 5 * SLOT);      // S5
  // Wk/Wv split pairs in S10/S11 during GEMMs only:
  u16* Wk_h = (u16*)(X + 10 * SLOT);
  u16* Wk_l = (u16*)(X + 10 * SLOT + CC * 2);
  u16* Wv_h = (u16*)(X + 11 * SLOT);
  u16* Wv_l = (u16*)(X + 11 * SLOT + CC * 2);

  // W region: split pair for Wr, reused for Wo at the end
  u16* Wh = (u16*)alloc(CC * 2);
  u16* Wl = (u16*)alloc(CC * 2);

  // L region: LoRA packs + small intermediates
  u16* w1t = (u16*)alloc((size_t)128 * 2048 * 2);
  u16* a1t = (u16*)alloc((size_t)128 * 2048 * 2);
  u16* v1t = (u16*)alloc((size_t)128 * 2048 * 2);
  u16* g1t_h = (u16*)alloc((size_t)128 * 2048 * 2);
  u16* g1t_l = (u16*)alloc((size_t)128 * 2048 * 2);
  u16* w2t = (u16*)alloc((size_t)2048 * 64 * 2);
  u16* a2t = (u16*)alloc((size_t)2048 * 64 * 2);
  u16* v2t = (u16*)alloc((size_t)2048 * 32 * 2);
  u16* g2t_h = (u16*)alloc((size_t)2048 * 128 * 2);
  u16* g2t_l = (u16*)alloc((size_t)2048 * 128 * 2);
  u16* hb_w = (u16*)alloc((size_t)Mdim * 64 * 2);
  u16* hb_a = (u16*)alloc((size_t)Mdim * 64 * 2);
  u16* hb_v = (u16*)alloc((size_t)Mdim * 32 * 2);
  u16* sig_h = (u16*)alloc((size_t)Mdim * 128 * 2);
  u16* sig_l = (u16*)alloc((size_t)Mdim * 128 * 2);

  size_t required = (size_t)(cur - (char*)d_ws);
  if (ws_size < required) {
    fill_kernel<<<(out_size + 255) / 256, 256, 0, stream>>>(
        (float*)d_out, (float)(ws_size >> 20), out_size);
    return;
  }

  // 1) token-shift prep
  prep_kernel<<<(int)(MC / 256), 256, 0, stream>>>(
      x, shiftS, x_r, x_w, x_k, x_v, x_a, x_g,
      xr_h, xr_l, xk_h, xk_l, xv_h, xv_l, xg_h, xg_l, xw, xa);

  // 2) LoRA weight packs (single fused launch)
  pack_all_kernel<<<6400, 256, 0, stream>>>(
      w1, a1, v1, g1, w2, a2, v2, g2,
      w1t, a1t, v1t, g1t_h, g1t_l, w2t, a2t, v2t, g2t_h, g2t_l);

  // 2b) fused cast of Wr/Wk/Wv split pairs (Wk->S10, Wv->S11)
  cast3_kernel<<<(int)(3 * CC / 256), 256, 0, stream>>>(
      Wr, Wh, Wl, Wk, Wk_h, Wk_l, Wv, Wv_h, Wv_l);

  // 3) merged LoRA-1 (w/a/v) + g1 split (concurrent, 128 blocks)
  dim3 gL1(Mdim / 128, 1, 4);
  lora1g_kernel<<<gL1, 256, 0, stream>>>(
      xw, xa, xv_h, w1t, a1t, v1t, hb_w, hb_a, hb_v,
      xg_h, xg_l, g1t_h, g1t_l, sig_h, sig_l);

  // 4) r projection (serial: frees S0S1 for k), then merged k+v projections
  dim3 gBig(Mdim / 128, Cdim / 128);
  gemm_split<0><<<gBig, 256, 0, stream>>>(xr_h, xr_l, Wh, Wl, r_f32, nullptr, Cdim, Cdim, Cdim);
  dim3 gKV(Mdim / 128, Cdim / 128, 2);
  kv2_kernel<<<gKV, 256, 0, stream>>>(
      xk_h, xk_l, Wk_h, Wk_l, k_f32,
      xv_h, xv_l, Wv_h, Wv_l, v_f32);

  // 5) LoRA-2 fused: ew (bf16), a (f32 over dead Wk/Wv pairs), vmix (in-place S6S7)
  dim3 gL2(Mdim / 128, Cdim / 128, 3);
  lora2_kernel<<<gL2, 256, 0, stream>>>(hb_w, hb_a, hb_v, w2t, a2t, v2t,
                                        ew_bf, a_f32, v_f32, w0, a0, v0, vfirst);

  // 6) post: kk-norm -> ain(S4S5)/bin(S2S3), k-scale in-place
  post_kernel<<<(Mdim * Hdim) / 4, 256, 0, stream>>>(
      k_f32, a_f32, k_k, k_a, ain_f, bin_f);

  // 7) scan v15
  scan_kernel<<<256, 512, 0, stream>>>(
      r_f32, ew_bf, k_f32, v_f32, ain_f, bin_f, wkv0, o_f32);

  // 8) LoRA-2 g (split, f32 -> S2S3, bin dead)
  gemm_split<0><<<gBig, 256, 0, stream>>>(sig_h, sig_l, g2t_h, g2t_l,
                                          g_f32, nullptr, 128, Cdim, Cdim);

  // 9) GroupNorm + bonus + gate -> og hi/lo (S4/S5)
  gn_kernel<<<(Mdim * Hdim) / 4, 256, 0, stream>>>(
      o_f32, r_f32, k_f32, v_f32, g_f32, r_k, ln_w, ln_b, og_h, og_l);

  // 10) output projection (Wr pair dead -> reuse Wh/Wl for Wo)
  cast_split_kernel<<<(int)(CC / 256), 256, 0, stream>>>(Wo, Wh, Wl);
  gemm_split<0><<<gBig, 256, 0, stream>>>(og_h, og_l, Wh, Wl,
                                          (float*)d_out, nullptr, Cdim, Cdim, Cdim);
}

// Round 22
// 952.966 us; speedup vs baseline: 1.1449x; 1.0444x over previous
//
#include <hip/hip_runtime.h>

#define Bdim 2
#define Tdim 2048
#define Cdim 2048
#define Hdim 32
#define Mdim (Bdim*Tdim)   // 4096

typedef unsigned short u16;
typedef short bf16x8 __attribute__((ext_vector_type(8)));
typedef float f32x2 __attribute__((ext_vector_type(2)));
typedef float f32x4 __attribute__((ext_vector_type(4)));

__device__ __forceinline__ u16 f2bf(float f) {
  unsigned u = __float_as_uint(f);
  u = (u + 0x7FFFu + ((u >> 16) & 1u)) >> 16;
  return (u16)u;
}
__device__ __forceinline__ float b2f(u16 h) {
  return __uint_as_float(((unsigned)h) << 16);
}
__device__ __forceinline__ float sigf(float x) { return 1.f / (1.f + expf(-x)); }

// async global->LDS, 16B per lane; LDS dest = wave-uniform base + lane*16
__device__ __forceinline__ void gld16(const u16* g, u16* l) {
  __builtin_amdgcn_global_load_lds(
      (const __attribute__((address_space(1))) unsigned int*)g,
      (__attribute__((address_space(3))) unsigned int*)l, 16, 0, 0);
}

// sum within each 16-lane DPP row via rotations: row_ror:8,4,2,1.
__device__ __forceinline__ float dpp_red16(float x) {
  int t = __builtin_amdgcn_mov_dpp(__float_as_int(x), 0x128, 0xF, 0xF, true);
  x += __int_as_float(t);
  t = __builtin_amdgcn_mov_dpp(__float_as_int(x), 0x124, 0xF, 0xF, true);
  x += __int_as_float(t);
  t = __builtin_amdgcn_mov_dpp(__float_as_int(x), 0x122, 0xF, 0xF, true);
  x += __int_as_float(t);
  t = __builtin_amdgcn_mov_dpp(__float_as_int(x), 0x121, 0xF, 0xF, true);
  x += __int_as_float(t);
  return x;
}

// full cross-half (lane^32) SUM via permlane32_swap builtin (R19-proven).
__device__ __forceinline__ float sum32(float x) {
#if __has_builtin(__builtin_amdgcn_permlane32_swap)
  typedef int int2v __attribute__((ext_vector_type(2)));
  int2v res = __builtin_amdgcn_permlane32_swap(__float_as_int(x), __float_as_int(x), false, false);
  return __int_as_float(res[0]) + __int_as_float(res[1]);
#else
  return x + __shfl_xor(x, 32);
#endif
}

// ---------------- diagnostic fill ----------------
__global__ __launch_bounds__(256) void fill_kernel(float* __restrict__ out, float v, int n) {
  int i = blockIdx.x * 256 + threadIdx.x;
  if (i < n) out[i] = v;
}

// ---------------- merged prep + LoRA packs + Wr/Wk/Wv casts (one launch) ----------------
// blocks [0,32768): token-shift prep; [32768,39168): 8 LoRA transposes;
// [39168,88320): Wr/Wk/Wv split casts.
__global__ __launch_bounds__(256) void prep_pack_cast_kernel(
    // prep
    const float* __restrict__ x, const float* __restrict__ shift,
    const float* __restrict__ mr, const float* __restrict__ mw,
    const float* __restrict__ mk, const float* __restrict__ mv,
    const float* __restrict__ ma, const float* __restrict__ mg,
    u16* __restrict__ xr_h, u16* __restrict__ xr_l,
    u16* __restrict__ xk_h, u16* __restrict__ xk_l,
    u16* __restrict__ xv_h, u16* __restrict__ xv_l,
    u16* __restrict__ xg_h, u16* __restrict__ xg_l,
    u16* __restrict__ xw, u16* __restrict__ xa,
    // packs
    const float* __restrict__ w1, const float* __restrict__ a1,
    const float* __restrict__ v1, const float* __restrict__ g1,
    const float* __restrict__ w2, const float* __restrict__ a2,
    const float* __restrict__ v2, const float* __restrict__ g2,
    u16* __restrict__ w1t, u16* __restrict__ a1t, u16* __restrict__ v1t,
    u16* __restrict__ g1t_h, u16* __restrict__ g1t_l,
    u16* __restrict__ w2t, u16* __restrict__ a2t, u16* __restrict__ v2t,
    u16* __restrict__ g2t_h, u16* __restrict__ g2t_l,
    // casts
    const float* __restrict__ Wr, u16* __restrict__ rh, u16* __restrict__ rl,
    const float* __restrict__ Wk, u16* __restrict__ kh, u16* __restrict__ kl,
    const float* __restrict__ Wv, u16* __restrict__ vh, u16* __restrict__ vl)
{
  int gbid = blockIdx.x;
  if (gbid < 32768) {
    // ---- prep ----
    size_t idx = (size_t)gbid * 256 + threadIdx.x;  // < M*C
    int c = (int)(idx & (Cdim - 1));
    size_t row = idx >> 11;
    int t = (int)(row & (Tdim - 1));
    int b = (int)(row >> 11);
    float xc = x[idx];
    float xp = (t == 0) ? shift[(size_t)b * Cdim + c] : x[idx - Cdim];
    float xx = xp - xc;

    float vr = xc + xx * mr[c];
    u16 hr = f2bf(vr); xr_h[idx] = hr; xr_l[idx] = f2bf(vr - b2f(hr));
    float vk = xc + xx * mk[c];
    u16 hk = f2bf(vk); xk_h[idx] = hk; xk_l[idx] = f2bf(vk - b2f(hk));
    float vv = xc + xx * mv[c];
    u16 hv = f2bf(vv); xv_h[idx] = hv; xv_l[idx] = f2bf(vv - b2f(hv));
    float vg = xc + xx * mg[c];
    u16 hg = f2bf(vg); xg_h[idx] = hg; xg_l[idx] = f2bf(vg - b2f(hg));

    xw[idx] = f2bf(xc + xx * mw[c]);
    xa[idx] = f2bf(xc + xx * ma[c]);
  } else if (gbid < 39168) {
    // ---- LoRA packs ----
    int bid = gbid - 32768;
    const float* src; u16* dh; u16* dl = nullptr;
    int K, Nsrc; size_t idx0;
    if (bid < 1024)      { src = w1; dh = w1t;   K = 2048; Nsrc = 64;   idx0 = (size_t)bid * 256; }
    else if (bid < 2048) { src = a1; dh = a1t;   K = 2048; Nsrc = 64;   idx0 = (size_t)(bid - 1024) * 256; }
    else if (bid < 3072) { src = v1; dh = v1t;   K = 2048; Nsrc = 32;   idx0 = (size_t)(bid - 2048) * 256; }
    else if (bid < 4096) { src = g1; dh = g1t_h; dl = g1t_l; K = 2048; Nsrc = 128; idx0 = (size_t)(bid - 3072) * 256; }
    else if (bid < 4608) { src = w2; dh = w2t;   K = 64;   Nsrc = 2048; idx0 = (size_t)(bid - 4096) * 256; }
    else if (bid < 5120) { src = a2; dh = a2t;   K = 64;   Nsrc = 2048; idx0 = (size_t)(bid - 4608) * 256; }
    else if (bid < 5376) { src = v2; dh = v2t;   K = 32;   Nsrc = 2048; idx0 = (size_t)(bid - 5120) * 256; }
    else                 { src = g2; dh = g2t_h; dl = g2t_l; K = 128;  Nsrc = 2048; idx0 = (size_t)(bid - 5376) * 256; }
    size_t idx = idx0 + threadIdx.x;
    int n = (int)(idx / K);
    int kk = (int)(idx - (size_t)n * K);
    float v = (n < Nsrc) ? src[(size_t)kk * Nsrc + n] : 0.f;
    u16 h = f2bf(v);
    dh[idx] = h;
    if (dl) dl[idx] = f2bf(v - b2f(h));
  } else {
    // ---- Wr/Wk/Wv split casts ----
    const size_t NB = (size_t)Cdim * Cdim / 256;   // 16384
    size_t bid = (size_t)(gbid - 39168);
    const float* src; u16* hi; u16* lo;
    if (bid < NB)            { src = Wr; hi = rh; lo = rl; }
    else if (bid < 2 * NB)   { src = Wk; hi = kh; lo = kl; bid -= NB; }
    else                     { src = Wv; hi = vh; lo = vl; bid -= 2 * NB; }
    size_t i = bid * 256 + threadIdx.x;
    float v = src[i];
    u16 h = f2bf(v);
    hi[i] = h;
    lo[i] = f2bf(v - b2f(h));
  }
}

// LDS bank swizzle (both-sides, rule 21): content[row][slot] = global[row][slot^(row&3)]

// ================= plain bf16 GEMM body (smem-pointer), 128x128, BK=32, 2-phase =================
// EP: 2 none/tanh(act)->bf16 | 3 ew=bf16(0.6065*sig(bias[n]+x))
//     4 a=f32 sig(bias[n]+x) | 5 vmix: f32 out = aux1 + (aux2-aux1)*sig(bias[n]+x)
template <int EP>
__device__ __forceinline__ void gemm_plain_body(
    char* smem, const u16* __restrict__ A, const u16* __restrict__ B, void* __restrict__ Cv,
    const float* __restrict__ bias, const float* __restrict__ aux1,
    const float* __restrict__ aux2, int K, int Nact, int ldC, int act)
{
  u16 (*As)[128][32] = (u16 (*)[128][32])smem;
  u16 (*Bs)[128][32] = (u16 (*)[128][32])(smem + 16384);
  int tid = threadIdx.x;
  int lane = tid & 63, wave = tid >> 6;
  int wm = wave >> 1, wn = wave & 1;
  int bm = blockIdx.x * 128, bn = blockIdx.y * 128;
  f32x4 zero = {0.f, 0.f, 0.f, 0.f};
  f32x4 acc[4][4];
#pragma unroll
  for (int i = 0; i < 4; i++)
#pragma unroll
    for (int j = 0; j < 4; j++) acc[i][j] = zero;
  int srow = tid >> 2;
  int sslot = tid & 3;
  int scol = (sslot ^ (srow & 3)) << 3;
  int dcol = sslot << 3;
  const u16* gA  = A + (size_t)(bm + srow) * K + scol;
  const u16* gA2 = A + (size_t)(bm + 64 + srow) * K + scol;
  const u16* gB  = B + (size_t)(bn + srow) * K + scol;
  const u16* gB2 = B + (size_t)(bn + 64 + srow) * K + scol;
  int fr = lane & 15;
  int fk = ((lane >> 4) << 3) ^ ((fr & 3) << 3);

#define STAGEP(buf, kk) { \
  gld16(gA + (kk), &As[buf][srow][dcol]); \
  gld16(gA2 + (kk), &As[buf][64 + srow][dcol]); \
  gld16(gB + (kk), &Bs[buf][srow][dcol]); \
  gld16(gB2 + (kk), &Bs[buf][64 + srow][dcol]); }

  STAGEP(0, 0)
  __syncthreads();
  int cur = 0;
  for (int k0 = 0; k0 < K; k0 += 32) {
    if (k0 + 32 < K) STAGEP(cur ^ 1, k0 + 32)
    bf16x8 af[4], bfv[4];
#pragma unroll
    for (int i = 0; i < 4; i++) af[i] = *(const bf16x8*)&As[cur][wm * 64 + i * 16 + fr][fk];
#pragma unroll
    for (int j = 0; j < 4; j++) bfv[j] = *(const bf16x8*)&Bs[cur][wn * 64 + j * 16 + fr][fk];
#pragma unroll
    for (int i = 0; i < 4; i++)
#pragma unroll
      for (int j = 0; j < 4; j++)
        acc[i][j] = __builtin_amdgcn_mfma_f32_16x16x32_bf16(af[i], bfv[j], acc[i][j], 0, 0, 0);
    __syncthreads();
    cur ^= 1;
  }
#undef STAGEP
  int rb = (lane >> 4) << 2;   // C/D: col=lane&15, row=(lane>>4)*4+reg [m89/m91]
  int cc = lane & 15;
#pragma unroll
  for (int i = 0; i < 4; i++) {
    int mm = bm + wm * 64 + i * 16 + rb;
#pragma unroll
    for (int j = 0; j < 4; j++) {
      int nn = bn + wn * 64 + j * 16 + cc;
      if (nn < Nact) {
#pragma unroll
        for (int r = 0; r < 4; r++) {
          float val = acc[i][j][r];
          size_t oidx = (size_t)(mm + r) * ldC + nn;
          if (EP == 2) {
            if (act == 1) val = tanhf(val);
            ((u16*)Cv)[oidx] = f2bf(val);
          }
          else if (EP == 3) ((u16*)Cv)[oidx] = f2bf(0.60653065971f * sigf(bias[nn] + val));
          else if (EP == 4) ((float*)Cv)[oidx] = sigf(bias[nn] + val);
          else if (EP == 5) {
            float vraw = aux1[oidx], vf = aux2[oidx];
            ((float*)Cv)[oidx] = vraw + (vf - vraw) * sigf(bias[nn] + val);
          }
        }
      }
    }
  }
}

// ================= split-bf16 GEMM body: TERMS=3: Ah*Bh+Ah*Bl+Al*Bh | TERMS=2: Ah*Bh+Ah*Bl =================
// smem usage: 65536 bytes. EP: 0 f32 | 1 sigmoid -> hi/lo pair
template <int EP, int TERMS>
__device__ __forceinline__ void gemm_split_body(
    char* smem, const u16* __restrict__ Ah, const u16* __restrict__ Al,
    const u16* __restrict__ Bh, const u16* __restrict__ Bl,
    void* __restrict__ C1, u16* __restrict__ C2, int K, int Nact, int ldC)
{
  u16 (*Ash)[128][32] = (u16 (*)[128][32])smem;
  u16 (*Asl)[128][32] = (u16 (*)[128][32])(smem + 16384);
  u16 (*Bsh)[128][32] = (u16 (*)[128][32])(smem + 32768);
  u16 (*Bsl)[128][32] = (u16 (*)[128][32])(smem + 49152);
  int tid = threadIdx.x;
  int lane = tid & 63, wave = tid >> 6;
  int wm = wave >> 1, wn = wave & 1;
  int bm = blockIdx.x * 128, bn = blockIdx.y * 128;
  f32x4 zero = {0.f, 0.f, 0.f, 0.f};
  f32x4 acc[4][4];
#pragma unroll
  for (int i = 0; i < 4; i++)
#pragma unroll
    for (int j = 0; j < 4; j++) acc[i][j] = zero;
  int srow = tid >> 2;
  int sslot = tid & 3;
  int scol = (sslot ^ (srow & 3)) << 3;
  int dcol = sslot << 3;
  size_t ga  = (size_t)(bm + srow) * K + scol;
  size_t ga2 = (size_t)(bm + 64 + srow) * K + scol;
  size_t gb  = (size_t)(bn + srow) * K + scol;
  size_t gb2 = (size_t)(bn + 64 + srow) * K + scol;
  int fr = lane & 15;
  int fk = ((lane >> 4) << 3) ^ ((fr & 3) << 3);

#define STAGES(buf, kk) { \
  gld16(Ah + ga + (kk), &Ash[buf][srow][dcol]); \
  gld16(Ah + ga2 + (kk), &Ash[buf][64 + srow][dcol]); \
  if (TERMS == 3) { \
    gld16(Al + ga + (kk), &Asl[buf][srow][dcol]); \
    gld16(Al + ga2 + (kk), &Asl[buf][64 + srow][dcol]); } \
  gld16(Bh + gb + (kk), &Bsh[buf][srow][dcol]); \
  gld16(Bh + gb2 + (kk), &Bsh[buf][64 + srow][dcol]); \
  gld16(Bl + gb + (kk), &Bsl[buf][srow][dcol]); \
  gld16(Bl + gb2 + (kk), &Bsl[buf][64 + srow][dcol]); }

  STAGES(0, 0)
  __syncthreads();
  int cur = 0;
  for (int k0 = 0; k0 < K; k0 += 32) {
    if (k0 + 32 < K) STAGES(cur ^ 1, k0 + 32)
    bf16x8 fah[4], fal[4], fbh[4], fbl[4];
#pragma unroll
    for (int i = 0; i < 4; i++) {
      fah[i] = *(const bf16x8*)&Ash[cur][wm * 64 + i * 16 + fr][fk];
      if (TERMS == 3) fal[i] = *(const bf16x8*)&Asl[cur][wm * 64 + i * 16 + fr][fk];
    }
#pragma unroll
    for (int j = 0; j < 4; j++) {
      fbh[j] = *(const bf16x8*)&Bsh[cur][wn * 64 + j * 16 + fr][fk];
      fbl[j] = *(const bf16x8*)&Bsl[cur][wn * 64 + j * 16 + fr][fk];
    }
#pragma unroll
    for (int i = 0; i < 4; i++)
#pragma unroll
      for (int j = 0; j < 4; j++) {
        acc[i][j] = __builtin_amdgcn_mfma_f32_16x16x32_bf16(fah[i], fbh[j], acc[i][j], 0, 0, 0);
        acc[i][j] = __builtin_amdgcn_mfma_f32_16x16x32_bf16(fah[i], fbl[j], acc[i][j], 0, 0, 0);
        if (TERMS == 3)
          acc[i][j] = __builtin_amdgcn_mfma_f32_16x16x32_bf16(fal[i], fbh[j], acc[i][j], 0, 0, 0);
      }
    __syncthreads();
    cur ^= 1;
  }
#undef STAGES
  int rb = (lane >> 4) << 2;
  int cc = lane & 15;
#pragma unroll
  for (int i = 0; i < 4; i++) {
    int mm = bm + wm * 64 + i * 16 + rb;
#pragma unroll
    for (int j = 0; j < 4; j++) {
      int nn = bn + wn * 64 + j * 16 + cc;
      if (nn < Nact) {
#pragma unroll
        for (int r = 0; r < 4; r++) {
          float val = acc[i][j][r];
          size_t oidx = (size_t)(mm + r) * ldC + nn;
          if (EP == 0) ((float*)C1)[oidx] = val;
          else {
            float s = sigf(val);
            u16 h = f2bf(s);
            ((u16*)C1)[oidx] = h;
            C2[oidx] = f2bf(s - b2f(h));
          }
        }
      }
    }
  }
}

// ---------------- wrappers ----------------
template <int EP, int TERMS>
__global__ __launch_bounds__(256) void gemm_split(
    const u16* Ah, const u16* Al, const u16* Bh, const u16* Bl,
    void* C1, u16* C2, int K, int Nact, int ldC)
{
  __shared__ __align__(16) char smem[65536];
  gemm_split_body<EP, TERMS>(smem, Ah, Al, Bh, Bl, C1, C2, K, Nact, ldC);
}

// merged LoRA-1 (z=0 w tanh, z=1 a, z=2 v) + g1 split sigmoid (z=3, 2-term) — concurrent
__global__ __launch_bounds__(256) void lora1g_kernel(
    const u16* A0, const u16* A1, const u16* A2,
    const u16* B0, const u16* B1, const u16* B2,
    u16* C0, u16* C1, u16* C2,
    const u16* Agh, const u16* Agl, const u16* Bgh, const u16* Bgl,
    u16* Cgh, u16* Cgl)
{
  __shared__ __align__(16) char smem[65536];
  int z = blockIdx.z;
  if (z < 3) {
    const u16* A = (z == 0) ? A0 : (z == 1) ? A1 : A2;
    const u16* B = (z == 0) ? B0 : (z == 1) ? B1 : B2;
    u16* C      = (z == 0) ? C0 : (z == 1) ? C1 : C2;
    int Nact    = (z == 0) ? 64 : (z == 1) ? 64 : 32;
    int act     = (z == 0) ? 1 : 0;
    gemm_plain_body<2>(smem, A, B, C, nullptr, nullptr, nullptr, 2048, Nact, Nact, act);
  } else {
    gemm_split_body<1, 2>(smem, Agh, Agl, Bgh, Bgl, Cgh, Cgl, 2048, 128, 128);
  }
}

// merged k+v projections (z=0: k, z=1: v) — disjoint buffers, concurrent
__global__ __launch_bounds__(256) void kv2_kernel(
    const u16* Akh, const u16* Akl, const u16* Bkh, const u16* Bkl, float* Ck,
    const u16* Avh, const u16* Avl, const u16* Bvh, const u16* Bvl, float* Cv2)
{
  __shared__ __align__(16) char smem[65536];
  if (blockIdx.z == 0)
    gemm_split_body<0, 3>(smem, Akh, Akl, Bkh, Bkl, Ck, nullptr, Cdim, Cdim, Cdim);
  else
    gemm_split_body<0, 3>(smem, Avh, Avl, Bvh, Bvl, Cv2, nullptr, Cdim, Cdim, Cdim);
}

// fused LoRA-2 (z: 0=ew EP3 K=64, 1=a EP4 K=64, 2=vmix EP5 K=32)
__global__ __launch_bounds__(256) void lora2_kernel(
    const u16* Aw, const u16* Aa, const u16* Av,
    const u16* Bw, const u16* Ba, const u16* Bv,
    u16* Cw, float* Ca, float* Cv,
    const float* w0, const float* a0, const float* v0,
    const float* vfirst)
{
  __shared__ __align__(16) char smem[32768];
  int z = blockIdx.z;
  if (z == 0)
    gemm_plain_body<3>(smem, Aw, Bw, Cw, w0, nullptr, nullptr, 64, Cdim, Cdim, 0);
  else if (z == 1)
    gemm_plain_body<4>(smem, Aa, Ba, Ca, a0, nullptr, nullptr, 64, Cdim, Cdim, 0);
  else
    gemm_plain_body<5>(smem, Av, Bv, Cv, v0, Cv, vfirst, 32, Cdim, Cdim, 0);
}

// ---------------- post: kk-norm + ain/bin + k-scale (one wave per (m,h)) ----------------
__global__ __launch_bounds__(256) void post_kernel(
    float* __restrict__ k, const float* __restrict__ a,
    const float* __restrict__ k_k, const float* __restrict__ k_a,
    float* __restrict__ ain, float* __restrict__ bin)
{
  int gid = blockIdx.x * 4 + (threadIdx.x >> 6);
  int lane = threadIdx.x & 63;
  int m = gid >> 5, h = gid & 31;
  int c = h * 64 + lane;
  size_t idx = (size_t)m * Cdim + c;

  float kr = k[idx];
  float av = a[idx];

  float kkv = kr * k_k[c];
  float ss = kkv * kkv;
#pragma unroll
  for (int off = 32; off; off >>= 1) ss += __shfl_xor(ss, off);
  float kkn = kkv / fmaxf(sqrtf(ss), 1e-12f);

  ain[idx] = -kkn;
  bin[idx] = kkn * av;
  k[idx] = kr * (1.f + (av - 1.f) * k_a[c]);
}

// ---------------- scan v15: LDS-shared 8-wave blocks + builtin permlane reduce ----------------
#define SG 32
__global__ __launch_bounds__(512) void scan_kernel(
    const float* __restrict__ r, const u16* __restrict__ ew,
    const float* __restrict__ k, const float* __restrict__ v,
    const float* __restrict__ ain, const float* __restrict__ bin,
    const float* __restrict__ S0, float* __restrict__ o)
{
  int bh = blockIdx.x & 63;
  int q4 = blockIdx.x >> 6;       // 0..3
  int tid = threadIdx.x;
  int wv = tid >> 6;              // 0..7
  int lane = tid & 63;
  int jci = (lane & 15) | ((lane >> 1) & 16);  // j-chunk 0..31
  int lr = (lane >> 4) & 1;                    // row bit
  int i = q4 * 16 + wv * 2 + lr;  // channel row 0..63
  int cb = (bh & 31) * 64;        // channel base
  size_t mbase = (size_t)(bh >> 5) * Tdim;   // row base in [M][C]

  float s0, s1;
  {
    const float* sp = S0 + (size_t)bh * 4096 + (size_t)i * 64 + jci * 2;
    s0 = sp[0]; s1 = sp[1];
  }

  __shared__ __align__(16) char lds[90112];

  f32x2 ak0a, ak0k, br0b, br0r;  unsigned e0r;
  f32x2 ak1a, ak1k, br1b, br1r;  unsigned e1r;
  f32x4 vv4;

#define SLOAD(gg) { \
  size_t gb_ = (mbase + (size_t)(gg) * SG) * Cdim + cb; \
  { int sub_ = tid >> 5, j_ = tid & 31; \
    size_t a_ = gb_ + (size_t)sub_ * Cdim + j_ * 2; \
    ak0a = *(const f32x2*)(ain + a_);  ak0k = *(const f32x2*)(k + a_); \
    br0b = *(const f32x2*)(bin + a_);  br0r = *(const f32x2*)(r + a_); \
    e0r  = *(const unsigned*)(ew + a_); } \
  { int sub_ = 16 + (tid >> 5), j_ = tid & 31; \
    size_t a_ = gb_ + (size_t)sub_ * Cdim + j_ * 2; \
    ak1a = *(const f32x2*)(ain + a_);  ak1k = *(const f32x2*)(k + a_); \
    br1b = *(const f32x2*)(bin + a_);  br1r = *(const f32x2*)(r + a_); \
    e1r  = *(const unsigned*)(ew + a_); } \
  { int sub_ = tid >> 4, ch_ = (tid & 15) * 4; \
    vv4 = *(const f32x4*)(v + gb_ + (size_t)sub_ * Cdim + ch_); } }

#define SWRITE(slot) { \
  char* b_ = lds + (slot) * 45056; \
  { int sub_ = tid >> 5, j_ = tid & 31; \
    f32x4 t_; t_[0] = ak0a[0]; t_[1] = ak0a[1]; t_[2] = ak0k[0]; t_[3] = ak0k[1]; \
    *(f32x4*)(b_ + sub_ * 512 + j_ * 16) = t_; \
    f32x4 u_; u_[0] = br0b[0]; u_[1] = br0b[1]; u_[2] = br0r[0]; u_[3] = br0r[1]; \
    *(f32x4*)(b_ + 16384 + sub_ * 512 + j_ * 16) = u_; \
    *(unsigned*)(b_ + 40960 + sub_ * 128 + j_ * 4) = e0r; } \
  { int sub_ = 16 + (tid >> 5), j_ = tid & 31; \
    f32x4 t_; t_[0] = ak1a[0]; t_[1] = ak1a[1]; t_[2] = ak1k[0]; t_[3] = ak1k[1]; \
    *(f32x4*)(b_ + sub_ * 512 + j_ * 16) = t_; \
    f32x4 u_; u_[0] = br1b[0]; u_[1] = br1b[1]; u_[2] = br1r[0]; u_[3] = br1r[1]; \
    *(f32x4*)(b_ + 16384 + sub_ * 512 + j_ * 16) = u_; \
    *(unsigned*)(b_ + 40960 + sub_ * 128 + j_ * 4) = e1r; } \
  { int sub_ = tid >> 4, ch_ = (tid & 15) * 4; \
    *(f32x4*)(b_ + 32768 + sub_ * 256 + ch_ * 4) = vv4; } }

  const int NG = Tdim / SG;   // 64
  SLOAD(0)
  SWRITE(0)
  SLOAD(1)
  __syncthreads();

  for (int g = 0; g < NG; ++g) {
    {
      char* b_ = lds + (g & 1) * 45056;
      size_t obase = (mbase + (size_t)g * SG) * Cdim + cb + i;
#pragma unroll
      for (int sub = 0; sub < SG; ++sub) {
        f32x4 akv = *(const f32x4*)(b_ + sub * 512 + jci * 16);
        f32x4 brv = *(const f32x4*)(b_ + 16384 + sub * 512 + jci * 16);
        float vi_ = *(const float*)(b_ + 32768 + sub * 256 + i * 4);
        unsigned e_ = *(const unsigned*)(b_ + 40960 + sub * 128 + jci * 4);
        float p_ = s0 * akv[0] + s1 * akv[1];
        p_ = dpp_red16(p_);
        p_ = sum32(p_);
        float e0_ = b2f((u16)(e_ & 0xFFFFu));
        float e1_ = b2f((u16)(e_ >> 16));
        float sn0_ = s0 * e0_ + p_ * brv[0] + vi_ * akv[2];
        float sn1_ = s1 * e1_ + p_ * brv[1] + vi_ * akv[3];
        s0 = sn0_; s1 = sn1_;
        float oo_ = sn0_ * brv[2] + sn1_ * brv[3];
        oo_ = dpp_red16(oo_);
        oo_ = sum32(oo_);
        if (jci == 0) o[obase + (size_t)sub * Cdim] = oo_;
      }
    }
    __syncthreads();
    if (g + 1 < NG) {
      SWRITE((g + 1) & 1)
      if (g + 2 < NG) SLOAD(g + 2)
      __syncthreads();
    }
  }
#undef SLOAD
#undef SWRITE
}

// ---------------- merged GroupNorm+bonus+gate (og_h only) + Wo split cast ----------------
// blocks [0,32768): gn; [32768,49152): Wo cast into Wh/Wl (dead since r GEMM).
__global__ __launch_bounds__(256) void gn_cast_kernel(
    const float* __restrict__ o_raw, const float* __restrict__ r,
    const float* __restrict__ k, const float* __restrict__ v,
    const float* __restrict__ g, const float* __restrict__ rkw,
    const float* __restrict__ ln_w, const float* __restrict__ ln_b,
    u16* __restrict__ og_h,
    const float* __restrict__ Wo, u16* __restrict__ Wh, u16* __restrict__ Wl)
{
  if (blockIdx.x < 32768) {
    int gid = blockIdx.x * 4 + (threadIdx.x >> 6);
    int lane = threadIdx.x & 63;
    int m = gid >> 5, h = gid & 31;
    int c = h * 64 + lane;
    size_t idx = (size_t)m * Cdim + c;

    float ov = o_raw[idx];
    float rv = r[idx], kv = k[idx], vv = v[idx];
    float rk = rv * kv * rkw[c];

    float s1 = ov, s2 = ov * ov, s3 = rk;
#pragma unroll
    for (int off = 32; off; off >>= 1) {
      s1 += __shfl_xor(s1, off);
      s2 += __shfl_xor(s2, off);
      s3 += __shfl_xor(s3, off);
    }
    float mu = s1 * (1.f / 64.f);
    float var = s2 * (1.f / 64.f) - mu * mu;
    float xh = (ov - mu) * rsqrtf(var + 6.4e-4f);   // eps = 1e-5 * 8^2
    float gn = xh * ln_w[c] + ln_b[c];
    float outp = (gn + s3 * vv) * g[idx];
    og_h[idx] = f2bf(outp);
  } else {
    size_t i = (size_t)(blockIdx.x - 32768) * 256 + threadIdx.x;
    float v = Wo[i];
    u16 h = f2bf(v);
    Wh[i] = h;
    Wl[i] = f2bf(v - b2f(h));
  }
}

// ---------------- host ----------------
extern "C" void kernel_launch(void* const* d_in, const int* in_sizes, int n_in,
                              void* d_out, int out_size, void* d_ws, size_t ws_size,
                              hipStream_t stream) {
  const float* x      = (const float*)d_in[0];
  const float* shiftS = (const float*)d_in[1];
  const float* vfirst = (const float*)d_in[2];
  const float* wkv0   = (const float*)d_in[3];
  const float* x_r = (const float*)d_in[4];
  const float* x_w = (const float*)d_in[5];
  const float* x_k = (const float*)d_in[6];
  const float* x_v = (const float*)d_in[7];
  const float* x_a = (const float*)d_in[8];
  const float* x_g = (const float*)d_in[9];
  const float* w0 = (const float*)d_in[10];
  const float* w1 = (const float*)d_in[11];
  const float* w2 = (const float*)d_in[12];
  const float* a0 = (const float*)d_in[13];
  const float* a1 = (const float*)d_in[14];
  const float* a2 = (const float*)d_in[15];
  const float* v0 = (const float*)d_in[16];
  const float* v1 = (const float*)d_in[17];
  const float* v2 = (const float*)d_in[18];
  const float* g1 = (const float*)d_in[19];
  const float* g2 = (const float*)d_in[20];
  const float* k_k = (const float*)d_in[21];
  const float* k_a = (const float*)d_in[22];
  const float* r_k = (const float*)d_in[23];
  const float* Wr = (const float*)d_in[24];
  const float* Wk = (const float*)d_in[25];
  const float* Wv = (const float*)d_in[26];
  const float* Wo = (const float*)d_in[27];
  const float* ln_w = (const float*)d_in[28];
  const float* ln_b = (const float*)d_in[29];
  (void)in_sizes; (void)n_in;

  const size_t MC = (size_t)Mdim * Cdim;      // 8,388,608
  const size_t CC = (size_t)Cdim * Cdim;
  const size_t SLOT = MC * 2;                 // 16 MiB

  char* cur = (char*)d_ws;
  auto alloc = [&](size_t bytes) -> void* {
    void* p = cur;
    cur += (bytes + 255) & ~(size_t)255;
    return p;
  };

  // X region: 13 slots, liveness-based reuse (all hazards stream-ordered).
  char* X = (char*)alloc(13 * SLOT);
  u16* xr_h = (u16*)(X + 0 * SLOT);
  u16* xr_l = (u16*)(X + 1 * SLOT);
  u16* xk_h = (u16*)(X + 2 * SLOT);
  u16* xk_l = (u16*)(X + 3 * SLOT);
  u16* xv_h = (u16*)(X + 4 * SLOT);
  u16* xv_l = (u16*)(X + 5 * SLOT);
  u16* xw   = (u16*)(X + 6 * SLOT);
  u16* xa   = (u16*)(X + 7 * SLOT);
  u16* xg_h = (u16*)(X + 8 * SLOT);
  u16* xg_l = (u16*)(X + 9 * SLOT);
  float* r_f32 = (float*)(X + 8 * SLOT);    // S8S9 (xg dead after lora1g)
  float* k_f32 = (float*)(X + 0 * SLOT);    // S0S1 (xr dead after r GEMM)
  float* v_f32 = (float*)(X + 6 * SLOT);    // S6S7 (xw,xa dead after lora1g)
  float* a_f32 = (float*)(X + 10 * SLOT);   // S10S11 (Wk/Wv pairs dead after kv2)
  u16*   ew_bf = (u16*)(X + 12 * SLOT);     // S12
  float* ain_f = (float*)(X + 4 * SLOT);    // S4S5 (xv dead after kv2)
  float* bin_f = (float*)(X + 2 * SLOT);    // S2S3 (xk dead after kv2)
  float* o_f32 = (float*)(X + 10 * SLOT);   // S10S11 (a dead after post)
  float* g_f32 = (float*)(X + 2 * SLOT);    // S2S3 (bin dead after scan)
  u16*   og_h  = (u16*)(X + 4 * SLOT);      // S4 (ain dead after scan)
  // Wk/Wv split pairs in S10/S11 during GEMMs only:
  u16* Wk_h = (u16*)(X + 10 * SLOT);
  u16* Wk_l = (u16*)(X + 10 * SLOT + CC * 2);
  u16* Wv_h = (u16*)(X + 11 * SLOT);
  u16* Wv_l = (u16*)(X + 11 * SLOT + CC * 2);

  // W region: split pair for Wr, reused for Wo at the end
  u16* Wh = (u16*)alloc(CC * 2);
  u16* Wl = (u16*)alloc(CC * 2);

  // L region: LoRA packs + small intermediates
  u16* w1t = (u16*)alloc((size_t)128 * 2048 * 2);
  u16* a1t = (u16*)alloc((size_t)128 * 2048 * 2);
  u16* v1t = (u16*)alloc((size_t)128 * 2048 * 2);
  u16* g1t_h = (u16*)alloc((size_t)128 * 2048 * 2);
  u16* g1t_l = (u16*)alloc((size_t)128 * 2048 * 2);
  u16* w2t = (u16*)alloc((size_t)2048 * 64 * 2);
  u16* a2t = (u16*)alloc((size_t)2048 * 64 * 2);
  u16* v2t = (u16*)alloc((size_t)2048 * 32 * 2);
  u16* g2t_h = (u16*)alloc((size_t)2048 * 128 * 2);
  u16* g2t_l = (u16*)alloc((size_t)2048 * 128 * 2);
  u16* hb_w = (u16*)alloc((size_t)Mdim * 64 * 2);
  u16* hb_a = (u16*)alloc((size_t)Mdim * 64 * 2);
  u16* hb_v = (u16*)alloc((size_t)Mdim * 32 * 2);
  u16* sig_h = (u16*)alloc((size_t)Mdim * 128 * 2);
  u16* sig_l = (u16*)alloc((size_t)Mdim * 128 * 2);

  size_t required = (size_t)(cur - (char*)d_ws);
  if (ws_size < required) {
    fill_kernel<<<(out_size + 255) / 256, 256, 0, stream>>>(
        (float*)d_out, (float)(ws_size >> 20), out_size);
    return;
  }

  // 1) merged prep + LoRA packs + Wr/Wk/Wv casts (one launch)
  prep_pack_cast_kernel<<<88320, 256, 0, stream>>>(
      x, shiftS, x_r, x_w, x_k, x_v, x_a, x_g,
      xr_h, xr_l, xk_h, xk_l, xv_h, xv_l, xg_h, xg_l, xw, xa,
      w1, a1, v1, g1, w2, a2, v2, g2,
      w1t, a1t, v1t, g1t_h, g1t_l, w2t, a2t, v2t, g2t_h, g2t_l,
      Wr, Wh, Wl, Wk, Wk_h, Wk_l, Wv, Wv_h, Wv_l);

  // 2) merged LoRA-1 (w/a/v) + g1 split (concurrent)
  dim3 gL1(Mdim / 128, 1, 4);
  lora1g_kernel<<<gL1, 256, 0, stream>>>(
      xw, xa, xv_h, w1t, a1t, v1t, hb_w, hb_a, hb_v,
      xg_h, xg_l, g1t_h, g1t_l, sig_h, sig_l);

  // 3) r projection (frees S0S1 for k), then merged k+v projections
  dim3 gBig(Mdim / 128, Cdim / 128);
  gemm_split<0, 3><<<gBig, 256, 0, stream>>>(xr_h, xr_l, Wh, Wl, r_f32, nullptr, Cdim, Cdim, Cdim);
  dim3 gKV(Mdim / 128, Cdim / 128, 2);
  kv2_kernel<<<gKV, 256, 0, stream>>>(
      xk_h, xk_l, Wk_h, Wk_l, k_f32,
      xv_h, xv_l, Wv_h, Wv_l, v_f32);

  // 4) LoRA-2 fused: ew (bf16), a (f32 over dead Wk/Wv pairs), vmix (in-place S6S7)
  dim3 gL2(Mdim / 128, Cdim / 128, 3);
  lora2_kernel<<<gL2, 256, 0, stream>>>(hb_w, hb_a, hb_v, w2t, a2t, v2t,
                                        ew_bf, a_f32, v_f32, w0, a0, v0, vfirst);

  // 5) post: kk-norm -> ain(S4S5)/bin(S2S3), k-scale in-place
  post_kernel<<<(Mdim * Hdim) / 4, 256, 0, stream>>>(
      k_f32, a_f32, k_k, k_a, ain_f, bin_f);

  // 6) scan v15
  scan_kernel<<<256, 512, 0, stream>>>(
      r_f32, ew_bf, k_f32, v_f32, ain_f, bin_f, wkv0, o_f32);

  // 7) LoRA-2 g (split 2-term, f32 -> S2S3, bin dead)
  gemm_split<0, 2><<<gBig, 256, 0, stream>>>(sig_h, sig_h, g2t_h, g2t_l,
                                             g_f32, nullptr, 128, Cdim, Cdim);

  // 8) merged GroupNorm (og_h only) + Wo cast (Wh/Wl dead since r GEMM)
  gn_cast_kernel<<<49152, 256, 0, stream>>>(
      o_f32, r_f32, k_f32, v_f32, g_f32, r_k, ln_w, ln_b, og_h, Wo, Wh, Wl);

  // 9) output projection: 2-term (og_h * (Wh+Wl)); dropped og_l term ~6e-4
  gemm_split<0, 2><<<gBig, 256, 0, stream>>>(og_h, og_h, Wh, Wl,
                                             (float*)d_out, nullptr, Cdim, Cdim, Cdim);
}

// Round 23
// 952.175 us; speedup vs baseline: 1.1459x; 1.0008x over previous
//
#include <hip/hip_runtime.h>

#define Bdim 2
#define Tdim 2048
#define Cdim 2048
#define Hdim 32
#define Mdim (Bdim*Tdim)   // 4096

typedef unsigned short u16;
typedef short bf16x8 __attribute__((ext_vector_type(8)));
typedef float f32x2 __attribute__((ext_vector_type(2)));
typedef float f32x4 __attribute__((ext_vector_type(4)));

__device__ __forceinline__ u16 f2bf(float f) {
  unsigned u = __float_as_uint(f);
  u = (u + 0x7FFFu + ((u >> 16) & 1u)) >> 16;
  return (u16)u;
}
__device__ __forceinline__ float b2f(u16 h) {
  return __uint_as_float(((unsigned)h) << 16);
}
__device__ __forceinline__ float sigf(float x) { return 1.f / (1.f + expf(-x)); }

// async global->LDS, 16B per lane; LDS dest = wave-uniform base + lane*16
__device__ __forceinline__ void gld16(const u16* g, u16* l) {
  __builtin_amdgcn_global_load_lds(
      (const __attribute__((address_space(1))) unsigned int*)g,
      (__attribute__((address_space(3))) unsigned int*)l, 16, 0, 0);
}

// sum within each 16-lane DPP row via rotations: row_ror:8,4,2,1.
__device__ __forceinline__ float dpp_red16(float x) {
  int t = __builtin_amdgcn_mov_dpp(__float_as_int(x), 0x128, 0xF, 0xF, true);
  x += __int_as_float(t);
  t = __builtin_amdgcn_mov_dpp(__float_as_int(x), 0x124, 0xF, 0xF, true);
  x += __int_as_float(t);
  t = __builtin_amdgcn_mov_dpp(__float_as_int(x), 0x122, 0xF, 0xF, true);
  x += __int_as_float(t);
  t = __builtin_amdgcn_mov_dpp(__float_as_int(x), 0x121, 0xF, 0xF, true);
  x += __int_as_float(t);
  return x;
}

// full cross-half (lane^32) SUM via permlane32_swap builtin (R19-proven).
__device__ __forceinline__ float sum32(float x) {
#if __has_builtin(__builtin_amdgcn_permlane32_swap)
  typedef int int2v __attribute__((ext_vector_type(2)));
  int2v res = __builtin_amdgcn_permlane32_swap(__float_as_int(x), __float_as_int(x), false, false);
  return __int_as_float(res[0]) + __int_as_float(res[1]);
#else
  return x + __shfl_xor(x, 32);
#endif
}

// ---------------- diagnostic fill ----------------
__global__ __launch_bounds__(256) void fill_kernel(float* __restrict__ out, float v, int n) {
  int i = blockIdx.x * 256 + threadIdx.x;
  if (i < n) out[i] = v;
}

// ---------------- merged prep + LoRA packs + Wr/Wk/Wv casts (one launch) ----------------
// blocks [0,32768): token-shift prep; [32768,39168): 8 LoRA transposes;
// [39168,88320): Wr/Wk/Wv split casts.
__global__ __launch_bounds__(256) void prep_pack_cast_kernel(
    const float* __restrict__ x, const float* __restrict__ shift,
    const float* __restrict__ mr, const float* __restrict__ mw,
    const float* __restrict__ mk, const float* __restrict__ mv,
    const float* __restrict__ ma, const float* __restrict__ mg,
    u16* __restrict__ xr_h, u16* __restrict__ xr_l,
    u16* __restrict__ xk_h, u16* __restrict__ xk_l,
    u16* __restrict__ xv_h, u16* __restrict__ xv_l,
    u16* __restrict__ xg_h, u16* __restrict__ xg_l,
    u16* __restrict__ xw, u16* __restrict__ xa,
    const float* __restrict__ w1, const float* __restrict__ a1,
    const float* __restrict__ v1, const float* __restrict__ g1,
    const float* __restrict__ w2, const float* __restrict__ a2,
    const float* __restrict__ v2, const float* __restrict__ g2,
    u16* __restrict__ w1t, u16* __restrict__ a1t, u16* __restrict__ v1t,
    u16* __restrict__ g1t_h, u16* __restrict__ g1t_l,
    u16* __restrict__ w2t, u16* __restrict__ a2t, u16* __restrict__ v2t,
    u16* __restrict__ g2t_h, u16* __restrict__ g2t_l,
    const float* __restrict__ Wr, u16* __restrict__ rh, u16* __restrict__ rl,
    const float* __restrict__ Wk, u16* __restrict__ kh, u16* __restrict__ kl,
    const float* __restrict__ Wv, u16* __restrict__ vh, u16* __restrict__ vl)
{
  int gbid = blockIdx.x;
  if (gbid < 32768) {
    size_t idx = (size_t)gbid * 256 + threadIdx.x;  // < M*C
    int c = (int)(idx & (Cdim - 1));
    size_t row = idx >> 11;
    int t = (int)(row & (Tdim - 1));
    int b = (int)(row >> 11);
    float xc = x[idx];
    float xp = (t == 0) ? shift[(size_t)b * Cdim + c] : x[idx - Cdim];
    float xx = xp - xc;

    float vr = xc + xx * mr[c];
    u16 hr = f2bf(vr); xr_h[idx] = hr; xr_l[idx] = f2bf(vr - b2f(hr));
    float vk = xc + xx * mk[c];
    u16 hk = f2bf(vk); xk_h[idx] = hk; xk_l[idx] = f2bf(vk - b2f(hk));
    float vv = xc + xx * mv[c];
    u16 hv = f2bf(vv); xv_h[idx] = hv; xv_l[idx] = f2bf(vv - b2f(hv));
    float vg = xc + xx * mg[c];
    u16 hg = f2bf(vg); xg_h[idx] = hg; xg_l[idx] = f2bf(vg - b2f(hg));

    xw[idx] = f2bf(xc + xx * mw[c]);
    xa[idx] = f2bf(xc + xx * ma[c]);
  } else if (gbid < 39168) {
    int bid = gbid - 32768;
    const float* src; u16* dh; u16* dl = nullptr;
    int K, Nsrc; size_t idx0;
    if (bid < 1024)      { src = w1; dh = w1t;   K = 2048; Nsrc = 64;   idx0 = (size_t)bid * 256; }
    else if (bid < 2048) { src = a1; dh = a1t;   K = 2048; Nsrc = 64;   idx0 = (size_t)(bid - 1024) * 256; }
    else if (bid < 3072) { src = v1; dh = v1t;   K = 2048; Nsrc = 32;   idx0 = (size_t)(bid - 2048) * 256; }
    else if (bid < 4096) { src = g1; dh = g1t_h; dl = g1t_l; K = 2048; Nsrc = 128; idx0 = (size_t)(bid - 3072) * 256; }
    else if (bid < 4608) { src = w2; dh = w2t;   K = 64;   Nsrc = 2048; idx0 = (size_t)(bid - 4096) * 256; }
    else if (bid < 5120) { src = a2; dh = a2t;   K = 64;   Nsrc = 2048; idx0 = (size_t)(bid - 4608) * 256; }
    else if (bid < 5376) { src = v2; dh = v2t;   K = 32;   Nsrc = 2048; idx0 = (size_t)(bid - 5120) * 256; }
    else                 { src = g2; dh = g2t_h; dl = g2t_l; K = 128;  Nsrc = 2048; idx0 = (size_t)(bid - 5376) * 256; }
    size_t idx = idx0 + threadIdx.x;
    int n = (int)(idx / K);
    int kk = (int)(idx - (size_t)n * K);
    float v = (n < Nsrc) ? src[(size_t)kk * Nsrc + n] : 0.f;
    u16 h = f2bf(v);
    dh[idx] = h;
    if (dl) dl[idx] = f2bf(v - b2f(h));
  } else {
    const size_t NB = (size_t)Cdim * Cdim / 256;   // 16384
    size_t bid = (size_t)(gbid - 39168);
    const float* src; u16* hi; u16* lo;
    if (bid < NB)            { src = Wr; hi = rh; lo = rl; }
    else if (bid < 2 * NB)   { src = Wk; hi = kh; lo = kl; bid -= NB; }
    else                     { src = Wv; hi = vh; lo = vl; bid -= 2 * NB; }
    size_t i = bid * 256 + threadIdx.x;
    float v = src[i];
    u16 h = f2bf(v);
    hi[i] = h;
    lo[i] = f2bf(v - b2f(h));
  }
}

// LDS bank swizzle (both-sides, rule 21): content[row][slot] = global[row][slot^(row&3)]

// ================= plain bf16 GEMM body (smem-pointer), 128x128, BK=32, 2-phase =================
// EP: 2 none/tanh(act)->bf16 | 3 ew=bf16(0.6065*sig(bias[n]+x))
//     4 a=f32 sig(bias[n]+x) | 5 vmix: f32 out = aux1 + (aux2-aux1)*sig(bias[n]+x)
template <int EP>
__device__ __forceinline__ void gemm_plain_body(
    char* smem, const u16* __restrict__ A, const u16* __restrict__ B, void* __restrict__ Cv,
    const float* __restrict__ bias, const float* __restrict__ aux1,
    const float* __restrict__ aux2, int K, int Nact, int ldC, int act)
{
  u16 (*As)[128][32] = (u16 (*)[128][32])smem;
  u16 (*Bs)[128][32] = (u16 (*)[128][32])(smem + 16384);
  int tid = threadIdx.x;
  int lane = tid & 63, wave = tid >> 6;
  int wm = wave >> 1, wn = wave & 1;
  int bm = blockIdx.x * 128, bn = blockIdx.y * 128;
  f32x4 zero = {0.f, 0.f, 0.f, 0.f};
  f32x4 acc[4][4];
#pragma unroll
  for (int i = 0; i < 4; i++)
#pragma unroll
    for (int j = 0; j < 4; j++) acc[i][j] = zero;
  int srow = tid >> 2;
  int sslot = tid & 3;
  int scol = (sslot ^ (srow & 3)) << 3;
  int dcol = sslot << 3;
  const u16* gA  = A + (size_t)(bm + srow) * K + scol;
  const u16* gA2 = A + (size_t)(bm + 64 + srow) * K + scol;
  const u16* gB  = B + (size_t)(bn + srow) * K + scol;
  const u16* gB2 = B + (size_t)(bn + 64 + srow) * K + scol;
  int fr = lane & 15;
  int fk = ((lane >> 4) << 3) ^ ((fr & 3) << 3);

#define STAGEP(buf, kk) { \
  gld16(gA + (kk), &As[buf][srow][dcol]); \
  gld16(gA2 + (kk), &As[buf][64 + srow][dcol]); \
  gld16(gB + (kk), &Bs[buf][srow][dcol]); \
  gld16(gB2 + (kk), &Bs[buf][64 + srow][dcol]); }

  STAGEP(0, 0)
  __syncthreads();
  int cur = 0;
  for (int k0 = 0; k0 < K; k0 += 32) {
    if (k0 + 32 < K) STAGEP(cur ^ 1, k0 + 32)
    bf16x8 af[4], bfv[4];
#pragma unroll
    for (int i = 0; i < 4; i++) af[i] = *(const bf16x8*)&As[cur][wm * 64 + i * 16 + fr][fk];
#pragma unroll
    for (int j = 0; j < 4; j++) bfv[j] = *(const bf16x8*)&Bs[cur][wn * 64 + j * 16 + fr][fk];
#pragma unroll
    for (int i = 0; i < 4; i++)
#pragma unroll
      for (int j = 0; j < 4; j++)
        acc[i][j] = __builtin_amdgcn_mfma_f32_16x16x32_bf16(af[i], bfv[j], acc[i][j], 0, 0, 0);
    __syncthreads();
    cur ^= 1;
  }
#undef STAGEP
  int rb = (lane >> 4) << 2;   // C/D: col=lane&15, row=(lane>>4)*4+reg [m89/m91]
  int cc = lane & 15;
#pragma unroll
  for (int i = 0; i < 4; i++) {
    int mm = bm + wm * 64 + i * 16 + rb;
#pragma unroll
    for (int j = 0; j < 4; j++) {
      int nn = bn + wn * 64 + j * 16 + cc;
      if (nn < Nact) {
#pragma unroll
        for (int r = 0; r < 4; r++) {
          float val = acc[i][j][r];
          size_t oidx = (size_t)(mm + r) * ldC + nn;
          if (EP == 2) {
            if (act == 1) val = tanhf(val);
            ((u16*)Cv)[oidx] = f2bf(val);
          }
          else if (EP == 3) ((u16*)Cv)[oidx] = f2bf(0.60653065971f * sigf(bias[nn] + val));
          else if (EP == 4) ((float*)Cv)[oidx] = sigf(bias[nn] + val);
          else if (EP == 5) {
            float vraw = aux1[oidx], vf = aux2[oidx];
            ((float*)Cv)[oidx] = vraw + (vf - vraw) * sigf(bias[nn] + val);
          }
        }
      }
    }
  }
}

// ================= split-bf16 GEMM body: TERMS=3: Ah*Bh+Ah*Bl+Al*Bh | TERMS=2: Ah*Bh+Ah*Bl =================
template <int EP, int TERMS>
__device__ __forceinline__ void gemm_split_body(
    char* smem, const u16* __restrict__ Ah, const u16* __restrict__ Al,
    const u16* __restrict__ Bh, const u16* __restrict__ Bl,
    void* __restrict__ C1, u16* __restrict__ C2, int K, int Nact, int ldC)
{
  u16 (*Ash)[128][32] = (u16 (*)[128][32])smem;
  u16 (*Asl)[128][32] = (u16 (*)[128][32])(smem + 16384);
  u16 (*Bsh)[128][32] = (u16 (*)[128][32])(smem + 32768);
  u16 (*Bsl)[128][32] = (u16 (*)[128][32])(smem + 49152);
  int tid = threadIdx.x;
  int lane = tid & 63, wave = tid >> 6;
  int wm = wave >> 1, wn = wave & 1;
  int bm = blockIdx.x * 128, bn = blockIdx.y * 128;
  f32x4 zero = {0.f, 0.f, 0.f, 0.f};
  f32x4 acc[4][4];
#pragma unroll
  for (int i = 0; i < 4; i++)
#pragma unroll
    for (int j = 0; j < 4; j++) acc[i][j] = zero;
  int srow = tid >> 2;
  int sslot = tid & 3;
  int scol = (sslot ^ (srow & 3)) << 3;
  int dcol = sslot << 3;
  size_t ga  = (size_t)(bm + srow) * K + scol;
  size_t ga2 = (size_t)(bm + 64 + srow) * K + scol;
  size_t gb  = (size_t)(bn + srow) * K + scol;
  size_t gb2 = (size_t)(bn + 64 + srow) * K + scol;
  int fr = lane & 15;
  int fk = ((lane >> 4) << 3) ^ ((fr & 3) << 3);

#define STAGES(buf, kk) { \
  gld16(Ah + ga + (kk), &Ash[buf][srow][dcol]); \
  gld16(Ah + ga2 + (kk), &Ash[buf][64 + srow][dcol]); \
  if (TERMS == 3) { \
    gld16(Al + ga + (kk), &Asl[buf][srow][dcol]); \
    gld16(Al + ga2 + (kk), &Asl[buf][64 + srow][dcol]); } \
  gld16(Bh + gb + (kk), &Bsh[buf][srow][dcol]); \
  gld16(Bh + gb2 + (kk), &Bsh[buf][64 + srow][dcol]); \
  gld16(Bl + gb + (kk), &Bsl[buf][srow][dcol]); \
  gld16(Bl + gb2 + (kk), &Bsl[buf][64 + srow][dcol]); }

  STAGES(0, 0)
  __syncthreads();
  int cur = 0;
  for (int k0 = 0; k0 < K; k0 += 32) {
    if (k0 + 32 < K) STAGES(cur ^ 1, k0 + 32)
    bf16x8 fah[4], fal[4], fbh[4], fbl[4];
#pragma unroll
    for (int i = 0; i < 4; i++) {
      fah[i] = *(const bf16x8*)&Ash[cur][wm * 64 + i * 16 + fr][fk];
      if (TERMS == 3) fal[i] = *(const bf16x8*)&Asl[cur][wm * 64 + i * 16 + fr][fk];
    }
#pragma unroll
    for (int j = 0; j < 4; j++) {
      fbh[j] = *(const bf16x8*)&Bsh[cur][wn * 64 + j * 16 + fr][fk];
      fbl[j] = *(const bf16x8*)&Bsl[cur][wn * 64 + j * 16 + fr][fk];
    }
#pragma unroll
    for (int i = 0; i < 4; i++)
#pragma unroll
      for (int j = 0; j < 4; j++) {
        acc[i][j] = __builtin_amdgcn_mfma_f32_16x16x32_bf16(fah[i], fbh[j], acc[i][j], 0, 0, 0);
        acc[i][j] = __builtin_amdgcn_mfma_f32_16x16x32_bf16(fah[i], fbl[j], acc[i][j], 0, 0, 0);
        if (TERMS == 3)
          acc[i][j] = __builtin_amdgcn_mfma_f32_16x16x32_bf16(fal[i], fbh[j], acc[i][j], 0, 0, 0);
      }
    __syncthreads();
    cur ^= 1;
  }
#undef STAGES
  int rb = (lane >> 4) << 2;
  int cc = lane & 15;
#pragma unroll
  for (int i = 0; i < 4; i++) {
    int mm = bm + wm * 64 + i * 16 + rb;
#pragma unroll
    for (int j = 0; j < 4; j++) {
      int nn = bn + wn * 64 + j * 16 + cc;
      if (nn < Nact) {
#pragma unroll
        for (int r = 0; r < 4; r++) {
          float val = acc[i][j][r];
          size_t oidx = (size_t)(mm + r) * ldC + nn;
          if (EP == 0) ((float*)C1)[oidx] = val;
          else {
            float s = sigf(val);
            u16 h = f2bf(s);
            ((u16*)C1)[oidx] = h;
            C2[oidx] = f2bf(s - b2f(h));
          }
        }
      }
    }
  }
}

// ---------------- wrappers ----------------
template <int EP, int TERMS>
__global__ __launch_bounds__(256) void gemm_split(
    const u16* Ah, const u16* Al, const u16* Bh, const u16* Bl,
    void* C1, u16* C2, int K, int Nact, int ldC)
{
  __shared__ __align__(16) char smem[65536];
  gemm_split_body<EP, TERMS>(smem, Ah, Al, Bh, Bl, C1, C2, K, Nact, ldC);
}

// merged LoRA-1 (z=0 w tanh, z=1 a, z=2 v) + g1 split sigmoid (z=3, 2-term)
__global__ __launch_bounds__(256) void lora1g_kernel(
    const u16* A0, const u16* A1, const u16* A2,
    const u16* B0, const u16* B1, const u16* B2,
    u16* C0, u16* C1, u16* C2,
    const u16* Agh, const u16* Agl, const u16* Bgh, const u16* Bgl,
    u16* Cgh, u16* Cgl)
{
  __shared__ __align__(16) char smem[65536];
  int z = blockIdx.z;
  if (z < 3) {
    const u16* A = (z == 0) ? A0 : (z == 1) ? A1 : A2;
    const u16* B = (z == 0) ? B0 : (z == 1) ? B1 : B2;
    u16* C      = (z == 0) ? C0 : (z == 1) ? C1 : C2;
    int Nact    = (z == 0) ? 64 : (z == 1) ? 64 : 32;
    int act     = (z == 0) ? 1 : 0;
    gemm_plain_body<2>(smem, A, B, C, nullptr, nullptr, nullptr, 2048, Nact, Nact, act);
  } else {
    gemm_split_body<1, 2>(smem, Agh, Agl, Bgh, Bgl, Cgh, Cgl, 2048, 128, 128);
  }
}

// merged r+k+v projections (z=0: r->S8S9, z=1: k->d_out, z=2: v->S6S7)
// read/write sets pairwise disjoint -> safe concurrency in one launch.
__global__ __launch_bounds__(256) void rkv3_kernel(
    const u16* Arh, const u16* Arl, const u16* Brh, const u16* Brl, float* Cr,
    const u16* Akh, const u16* Akl, const u16* Bkh, const u16* Bkl, float* Ck,
    const u16* Avh, const u16* Avl, const u16* Bvh, const u16* Bvl, float* Cv2)
{
  __shared__ __align__(16) char smem[65536];
  int z = blockIdx.z;
  if (z == 0)
    gemm_split_body<0, 3>(smem, Arh, Arl, Brh, Brl, Cr, nullptr, Cdim, Cdim, Cdim);
  else if (z == 1)
    gemm_split_body<0, 3>(smem, Akh, Akl, Bkh, Bkl, Ck, nullptr, Cdim, Cdim, Cdim);
  else
    gemm_split_body<0, 3>(smem, Avh, Avl, Bvh, Bvl, Cv2, nullptr, Cdim, Cdim, Cdim);
}

// fused LoRA-2 (z: 0=ew EP3 K=64, 1=a EP4 K=64, 2=vmix EP5 K=32)
__global__ __launch_bounds__(256) void lora2_kernel(
    const u16* Aw, const u16* Aa, const u16* Av,
    const u16* Bw, const u16* Ba, const u16* Bv,
    u16* Cw, float* Ca, float* Cv,
    const float* w0, const float* a0, const float* v0,
    const float* vfirst)
{
  __shared__ __align__(16) char smem[32768];
  int z = blockIdx.z;
  if (z == 0)
    gemm_plain_body<3>(smem, Aw, Bw, Cw, w0, nullptr, nullptr, 64, Cdim, Cdim, 0);
  else if (z == 1)
    gemm_plain_body<4>(smem, Aa, Ba, Ca, a0, nullptr, nullptr, 64, Cdim, Cdim, 0);
  else
    gemm_plain_body<5>(smem, Av, Bv, Cv, v0, Cv, vfirst, 32, Cdim, Cdim, 0);
}

// ---------------- merged post (kk-norm/ain/bin/k-scale) + Wo split cast ----------------
// blocks [0,32768): post; [32768,49152): Wo cast into Wh/Wl (dead since rkv).
__global__ __launch_bounds__(256) void post_cast_kernel(
    float* __restrict__ k, const float* __restrict__ a,
    const float* __restrict__ k_k, const float* __restrict__ k_a,
    float* __restrict__ ain, float* __restrict__ bin,
    const float* __restrict__ Wo, u16* __restrict__ Wh, u16* __restrict__ Wl)
{
  if (blockIdx.x < 32768) {
    int gid = blockIdx.x * 4 + (threadIdx.x >> 6);   // wave id over M*H
    int lane = threadIdx.x & 63;
    int m = gid >> 5, h = gid & 31;
    int c = h * 64 + lane;
    size_t idx = (size_t)m * Cdim + c;

    float kr = k[idx];
    float av = a[idx];

    float kkv = kr * k_k[c];
    float ss = kkv * kkv;
#pragma unroll
    for (int off = 32; off; off >>= 1) ss += __shfl_xor(ss, off);
    float kkn = kkv / fmaxf(sqrtf(ss), 1e-12f);

    ain[idx] = -kkn;
    bin[idx] = kkn * av;
    k[idx] = kr * (1.f + (av - 1.f) * k_a[c]);
  } else {
    size_t i = (size_t)(blockIdx.x - 32768) * 256 + threadIdx.x;
    float v = Wo[i];
    u16 h = f2bf(v);
    Wh[i] = h;
    Wl[i] = f2bf(v - b2f(h));
  }
}

// ---------------- scan v15: LDS-shared 8-wave blocks + builtin permlane reduce ----------------
#define SG 32
__global__ __launch_bounds__(512) void scan_kernel(
    const float* __restrict__ r, const u16* __restrict__ ew,
    const float* __restrict__ k, const float* __restrict__ v,
    const float* __restrict__ ain, const float* __restrict__ bin,
    const float* __restrict__ S0, float* __restrict__ o)
{
  int bh = blockIdx.x & 63;
  int q4 = blockIdx.x >> 6;       // 0..3
  int tid = threadIdx.x;
  int wv = tid >> 6;              // 0..7
  int lane = tid & 63;
  int jci = (lane & 15) | ((lane >> 1) & 16);  // j-chunk 0..31
  int lr = (lane >> 4) & 1;                    // row bit
  int i = q4 * 16 + wv * 2 + lr;  // channel row 0..63
  int cb = (bh & 31) * 64;        // channel base
  size_t mbase = (size_t)(bh >> 5) * Tdim;   // row base in [M][C]

  float s0, s1;
  {
    const float* sp = S0 + (size_t)bh * 4096 + (size_t)i * 64 + jci * 2;
    s0 = sp[0]; s1 = sp[1];
  }

  __shared__ __align__(16) char lds[90112];

  f32x2 ak0a, ak0k, br0b, br0r;  unsigned e0r;
  f32x2 ak1a, ak1k, br1b, br1r;  unsigned e1r;
  f32x4 vv4;

#define SLOAD(gg) { \
  size_t gb_ = (mbase + (size_t)(gg) * SG) * Cdim + cb; \
  { int sub_ = tid >> 5, j_ = tid & 31; \
    size_t a_ = gb_ + (size_t)sub_ * Cdim + j_ * 2; \
    ak0a = *(const f32x2*)(ain + a_);  ak0k = *(const f32x2*)(k + a_); \
    br0b = *(const f32x2*)(bin + a_);  br0r = *(const f32x2*)(r + a_); \
    e0r  = *(const unsigned*)(ew + a_); } \
  { int sub_ = 16 + (tid >> 5), j_ = tid & 31; \
    size_t a_ = gb_ + (size_t)sub_ * Cdim + j_ * 2; \
    ak1a = *(const f32x2*)(ain + a_);  ak1k = *(const f32x2*)(k + a_); \
    br1b = *(const f32x2*)(bin + a_);  br1r = *(const f32x2*)(r + a_); \
    e1r  = *(const unsigned*)(ew + a_); } \
  { int sub_ = tid >> 4, ch_ = (tid & 15) * 4; \
    vv4 = *(const f32x4*)(v + gb_ + (size_t)sub_ * Cdim + ch_); } }

#define SWRITE(slot) { \
  char* b_ = lds + (slot) * 45056; \
  { int sub_ = tid >> 5, j_ = tid & 31; \
    f32x4 t_; t_[0] = ak0a[0]; t_[1] = ak0a[1]; t_[2] = ak0k[0]; t_[3] = ak0k[1]; \
    *(f32x4*)(b_ + sub_ * 512 + j_ * 16) = t_; \
    f32x4 u_; u_[0] = br0b[0]; u_[1] = br0b[1]; u_[2] = br0r[0]; u_[3] = br0r[1]; \
    *(f32x4*)(b_ + 16384 + sub_ * 512 + j_ * 16) = u_; \
    *(unsigned*)(b_ + 40960 + sub_ * 128 + j_ * 4) = e0r; } \
  { int sub_ = 16 + (tid >> 5), j_ = tid & 31; \
    f32x4 t_; t_[0] = ak1a[0]; t_[1] = ak1a[1]; t_[2] = ak1k[0]; t_[3] = ak1k[1]; \
    *(f32x4*)(b_ + sub_ * 512 + j_ * 16) = t_; \
    f32x4 u_; u_[0] = br1b[0]; u_[1] = br1b[1]; u_[2] = br1r[0]; u_[3] = br1r[1]; \
    *(f32x4*)(b_ + 16384 + sub_ * 512 + j_ * 16) = u_; \
    *(unsigned*)(b_ + 40960 + sub_ * 128 + j_ * 4) = e1r; } \
  { int sub_ = tid >> 4, ch_ = (tid & 15) * 4; \
    *(f32x4*)(b_ + 32768 + sub_ * 256 + ch_ * 4) = vv4; } }

  const int NG = Tdim / SG;   // 64
  SLOAD(0)
  SWRITE(0)
  SLOAD(1)
  __syncthreads();

  for (int g = 0; g < NG; ++g) {
    {
      char* b_ = lds + (g & 1) * 45056;
      size_t obase = (mbase + (size_t)g * SG) * Cdim + cb + i;
#pragma unroll
      for (int sub = 0; sub < SG; ++sub) {
        f32x4 akv = *(const f32x4*)(b_ + sub * 512 + jci * 16);
        f32x4 brv = *(const f32x4*)(b_ + 16384 + sub * 512 + jci * 16);
        float vi_ = *(const float*)(b_ + 32768 + sub * 256 + i * 4);
        unsigned e_ = *(const unsigned*)(b_ + 40960 + sub * 128 + jci * 4);
        float p_ = s0 * akv[0] + s1 * akv[1];
        p_ = dpp_red16(p_);
        p_ = sum32(p_);
        float e0_ = b2f((u16)(e_ & 0xFFFFu));
        float e1_ = b2f((u16)(e_ >> 16));
        float sn0_ = s0 * e0_ + p_ * brv[0] + vi_ * akv[2];
        float sn1_ = s1 * e1_ + p_ * brv[1] + vi_ * akv[3];
        s0 = sn0_; s1 = sn1_;
        float oo_ = sn0_ * brv[2] + sn1_ * brv[3];
        oo_ = dpp_red16(oo_);
        oo_ = sum32(oo_);
        if (jci == 0) o[obase + (size_t)sub * Cdim] = oo_;
      }
    }
    __syncthreads();
    if (g + 1 < NG) {
      SWRITE((g + 1) & 1)
      if (g + 2 < NG) SLOAD(g + 2)
      __syncthreads();
    }
  }
#undef SLOAD
#undef SWRITE
}

// ---------------- GroupNorm + bonus + gate -> og_h ----------------
__global__ __launch_bounds__(256) void gn_kernel(
    const float* __restrict__ o_raw, const float* __restrict__ r,
    const float* __restrict__ k, const float* __restrict__ v,
    const float* __restrict__ g, const float* __restrict__ rkw,
    const float* __restrict__ ln_w, const float* __restrict__ ln_b,
    u16* __restrict__ og_h)
{
  int gid = blockIdx.x * 4 + (threadIdx.x >> 6);
  int lane = threadIdx.x & 63;
  int m = gid >> 5, h = gid & 31;
  int c = h * 64 + lane;
  size_t idx = (size_t)m * Cdim + c;

  float ov = o_raw[idx];
  float rv = r[idx], kv = k[idx], vv = v[idx];
  float rk = rv * kv * rkw[c];

  float s1 = ov, s2 = ov * ov, s3 = rk;
#pragma unroll
  for (int off = 32; off; off >>= 1) {
    s1 += __shfl_xor(s1, off);
    s2 += __shfl_xor(s2, off);
    s3 += __shfl_xor(s3, off);
  }
  float mu = s1 * (1.f / 64.f);
  float var = s2 * (1.f / 64.f) - mu * mu;
  float xh = (ov - mu) * rsqrtf(var + 6.4e-4f);   // eps = 1e-5 * 8^2
  float gn = xh * ln_w[c] + ln_b[c];
  float outp = (gn + s3 * vv) * g[idx];
  og_h[idx] = f2bf(outp);
}

// ---------------- host ----------------
extern "C" void kernel_launch(void* const* d_in, const int* in_sizes, int n_in,
                              void* d_out, int out_size, void* d_ws, size_t ws_size,
                              hipStream_t stream) {
  const float* x      = (const float*)d_in[0];
  const float* shiftS = (const float*)d_in[1];
  const float* vfirst = (const float*)d_in[2];
  const float* wkv0   = (const float*)d_in[3];
  const float* x_r = (const float*)d_in[4];
  const float* x_w = (const float*)d_in[5];
  const float* x_k = (const float*)d_in[6];
  const float* x_v = (const float*)d_in[7];
  const float* x_a = (const float*)d_in[8];
  const float* x_g = (const float*)d_in[9];
  const float* w0 = (const float*)d_in[10];
  const float* w1 = (const float*)d_in[11];
  const float* w2 = (const float*)d_in[12];
  const float* a0 = (const float*)d_in[13];
  const float* a1 = (const float*)d_in[14];
  const float* a2 = (const float*)d_in[15];
  const float* v0 = (const float*)d_in[16];
  const float* v1 = (const float*)d_in[17];
  const float* v2 = (const float*)d_in[18];
  const float* g1 = (const float*)d_in[19];
  const float* g2 = (const float*)d_in[20];
  const float* k_k = (const float*)d_in[21];
  const float* k_a = (const float*)d_in[22];
  const float* r_k = (const float*)d_in[23];
  const float* Wr = (const float*)d_in[24];
  const float* Wk = (const float*)d_in[25];
  const float* Wv = (const float*)d_in[26];
  const float* Wo = (const float*)d_in[27];
  const float* ln_w = (const float*)d_in[28];
  const float* ln_b = (const float*)d_in[29];
  (void)in_sizes; (void)n_in;

  const size_t MC = (size_t)Mdim * Cdim;      // 8,388,608
  const size_t CC = (size_t)Cdim * Cdim;
  const size_t SLOT = MC * 2;                 // 16 MiB

  char* cur = (char*)d_ws;
  auto alloc = [&](size_t bytes) -> void* {
    void* p = cur;
    cur += (bytes + 255) & ~(size_t)255;
    return p;
  };

  // X region: 13 slots, liveness-based reuse (all hazards stream-ordered).
  // k_f32 lives in d_out (scratch until final Wo GEMM overwrites it).
  char* X = (char*)alloc(13 * SLOT);
  u16* xr_h = (u16*)(X + 0 * SLOT);
  u16* xr_l = (u16*)(X + 1 * SLOT);
  u16* xk_h = (u16*)(X + 2 * SLOT);
  u16* xk_l = (u16*)(X + 3 * SLOT);
  u16* xv_h = (u16*)(X + 4 * SLOT);
  u16* xv_l = (u16*)(X + 5 * SLOT);
  u16* xw   = (u16*)(X + 6 * SLOT);
  u16* xa   = (u16*)(X + 7 * SLOT);
  u16* xg_h = (u16*)(X + 8 * SLOT);
  u16* xg_l = (u16*)(X + 9 * SLOT);
  float* r_f32 = (float*)(X + 8 * SLOT);    // S8S9 (xg dead after lora1g)
  float* k_f32 = (float*)d_out;             // d_out scratch (overwritten by Wo GEMM)
  float* v_f32 = (float*)(X + 6 * SLOT);    // S6S7 (xw,xa dead after lora1g)
  float* a_f32 = (float*)(X + 10 * SLOT);   // S10S11 (Wk/Wv pairs dead after rkv)
  u16*   ew_bf = (u16*)(X + 12 * SLOT);     // S12
  float* ain_f = (float*)(X + 4 * SLOT);    // S4S5 (xv dead after rkv)
  float* bin_f = (float*)(X + 2 * SLOT);    // S2S3 (xk dead after rkv)
  float* o_f32 = (float*)(X + 10 * SLOT);   // S10S11 (a dead after post)
  float* g_f32 = (float*)(X + 2 * SLOT);    // S2S3 (bin dead after scan)
  u16*   og_h  = (u16*)(X + 4 * SLOT);      // S4 (ain dead after scan)
  // Wk/Wv split pairs in S10/S11 during GEMMs only:
  u16* Wk_h = (u16*)(X + 10 * SLOT);
  u16* Wk_l = (u16*)(X + 10 * SLOT + CC * 2);
  u16* Wv_h = (u16*)(X + 11 * SLOT);
  u16* Wv_l = (u16*)(X + 11 * SLOT + CC * 2);

  // W region: split pair for Wr, reused for Wo at the end
  u16* Wh = (u16*)alloc(CC * 2);
  u16* Wl = (u16*)alloc(CC * 2);

  // L region: LoRA packs + small intermediates
  u16* w1t = (u16*)alloc((size_t)128 * 2048 * 2);
  u16* a1t = (u16*)alloc((size_t)128 * 2048 * 2);
  u16* v1t = (u16*)alloc((size_t)128 * 2048 * 2);
  u16* g1t_h = (u16*)alloc((size_t)128 * 2048 * 2);
  u16* g1t_l = (u16*)alloc((size_t)128 * 2048 * 2);
  u16* w2t = (u16*)alloc((size_t)2048 * 64 * 2);
  u16* a2t = (u16*)alloc((size_t)2048 * 64 * 2);
  u16* v2t = (u16*)alloc((size_t)2048 * 32 * 2);
  u16* g2t_h = (u16*)alloc((size_t)2048 * 128 * 2);
  u16* g2t_l = (u16*)alloc((size_t)2048 * 128 * 2);
  u16* hb_w = (u16*)alloc((size_t)Mdim * 64 * 2);
  u16* hb_a = (u16*)alloc((size_t)Mdim * 64 * 2);
  u16* hb_v = (u16*)alloc((size_t)Mdim * 32 * 2);
  u16* sig_h = (u16*)alloc((size_t)Mdim * 128 * 2);
  u16* sig_l = (u16*)alloc((size_t)Mdim * 128 * 2);

  size_t required = (size_t)(cur - (char*)d_ws);
  if (ws_size < required) {
    fill_kernel<<<(out_size + 255) / 256, 256, 0, stream>>>(
        (float*)d_out, (float)(ws_size >> 20), out_size);
    return;
  }

  // 1) merged prep + LoRA packs + Wr/Wk/Wv casts
  prep_pack_cast_kernel<<<88320, 256, 0, stream>>>(
      x, shiftS, x_r, x_w, x_k, x_v, x_a, x_g,
      xr_h, xr_l, xk_h, xk_l, xv_h, xv_l, xg_h, xg_l, xw, xa,
      w1, a1, v1, g1, w2, a2, v2, g2,
      w1t, a1t, v1t, g1t_h, g1t_l, w2t, a2t, v2t, g2t_h, g2t_l,
      Wr, Wh, Wl, Wk, Wk_h, Wk_l, Wv, Wv_h, Wv_l);

  // 2) merged LoRA-1 (w/a/v) + g1 split
  dim3 gL1(Mdim / 128, 1, 4);
  lora1g_kernel<<<gL1, 256, 0, stream>>>(
      xw, xa, xv_h, w1t, a1t, v1t, hb_w, hb_a, hb_v,
      xg_h, xg_l, g1t_h, g1t_l, sig_h, sig_l);

  // 3) merged r+k+v projections (r->S8S9, k->d_out, v->S6S7)
  dim3 gRKV(Mdim / 128, Cdim / 128, 3);
  rkv3_kernel<<<gRKV, 256, 0, stream>>>(
      xr_h, xr_l, Wh, Wl, r_f32,
      xk_h, xk_l, Wk_h, Wk_l, k_f32,
      xv_h, xv_l, Wv_h, Wv_l, v_f32);

  // 4) LoRA-2 fused: ew (bf16), a (f32 over dead Wk/Wv pairs), vmix (in-place S6S7)
  dim3 gL2(Mdim / 128, Cdim / 128, 3);
  lora2_kernel<<<gL2, 256, 0, stream>>>(hb_w, hb_a, hb_v, w2t, a2t, v2t,
                                        ew_bf, a_f32, v_f32, w0, a0, v0, vfirst);

  // 5) merged post (ain->S4S5, bin->S2S3, k-scale in d_out) + Wo cast (Wh/Wl dead)
  post_cast_kernel<<<49152, 256, 0, stream>>>(
      k_f32, a_f32, k_k, k_a, ain_f, bin_f, Wo, Wh, Wl);

  // 6) scan v15
  scan_kernel<<<256, 512, 0, stream>>>(
      r_f32, ew_bf, k_f32, v_f32, ain_f, bin_f, wkv0, o_f32);

  // 7) LoRA-2 g (2-term, f32 -> S2S3, bin dead)
  gemm_split<0, 2><<<dim3(Mdim / 128, Cdim / 128), 256, 0, stream>>>(
      sig_h, sig_h, g2t_h, g2t_l, g_f32, nullptr, 128, Cdim, Cdim);

  // 8) GroupNorm + bonus + gate -> og_h (reads k from d_out before it's overwritten)
  gn_kernel<<<32768, 256, 0, stream>>>(
      o_f32, r_f32, k_f32, v_f32, g_f32, r_k, ln_w, ln_b, og_h);

  // 9) output projection: 2-term (og_h * (Wh+Wl)) -> d_out
  gemm_split<0, 2><<<dim3(Mdim / 128, Cdim / 128), 256, 0, stream>>>(
      og_h, og_h, Wh, Wl, (float*)d_out, nullptr, Cdim, Cdim, Cdim);
}